// Round 1
// baseline (4810.020 us; speedup 1.0000x reference)
//
#include <hip/hip_runtime.h>
#include <math.h>

#define D 128
#define NG 64
#define NSTEPS 5

__device__ __forceinline__ float sigf(float x) { return 1.f / (1.f + expf(-x)); }
__device__ __forceinline__ float lrelu(float x) { return x > 0.f ? x : 0.2f * x; }

// ---------- transpose W[rows][cols] -> WT[cols][rows] ----------
__global__ void k_transpose(const float* __restrict__ W, float* __restrict__ WT,
                            int rows, int cols) {
  int n = rows * cols;
  for (int i = blockIdx.x * blockDim.x + threadIdx.x; i < n; i += gridDim.x * blockDim.x) {
    int r = i / cols, c = i - r * cols;
    WT[c * rows + r] = W[i];
  }
}

// ---------- CSR build ----------
__global__ void k_hist(const int* __restrict__ dst, int E, int* __restrict__ deg) {
  for (int e = blockIdx.x * blockDim.x + threadIdx.x; e < E; e += gridDim.x * blockDim.x)
    atomicAdd(&deg[dst[e]], 1);
}

__global__ __launch_bounds__(1024) void k_scan(const int* __restrict__ deg,
    int* __restrict__ row_ofs, int* __restrict__ cursor, int N) {
  __shared__ int sh[1024];
  __shared__ int run_s;
  int tid = threadIdx.x;
  if (tid == 0) { row_ofs[0] = 0; run_s = 0; }
  __syncthreads();
  for (int base = 0; base < N; base += 1024) {
    int i = base + tid;
    int v = (i < N) ? deg[i] : 0;
    sh[tid] = v;
    __syncthreads();
    for (int off = 1; off < 1024; off <<= 1) {
      int y = (tid >= off) ? sh[tid - off] : 0;
      __syncthreads();
      sh[tid] += y;
      __syncthreads();
    }
    int incl = sh[tid];
    int run = run_s;
    if (i < N) {
      row_ofs[i + 1] = run + incl;
      cursor[i] = run + incl - v;
    }
    int total = sh[1023];
    __syncthreads();
    if (tid == 0) run_s = run + total;
    __syncthreads();
  }
}

__global__ void k_scatter(const int* __restrict__ src, const int* __restrict__ dst,
                          const int* __restrict__ ety, int E, int* __restrict__ cursor,
                          int* __restrict__ csr_src, int* __restrict__ csr_row) {
  for (int e = blockIdx.x * blockDim.x + threadIdx.x; e < E; e += gridDim.x * blockDim.x) {
    int p = atomicAdd(&cursor[dst[e]], 1);
    int s = src[e];
    csr_src[p] = s;
    csr_row[p] = s * 4 + ety[e];
  }
}

__global__ void k_goffs(const int* __restrict__ gid, int N,
                        int* __restrict__ goffs, int* __restrict__ gcnt) {
  __shared__ int cnt[NG];
  int tid = threadIdx.x;
  if (tid < NG) cnt[tid] = 0;
  __syncthreads();
  for (int i = tid; i < N; i += blockDim.x) atomicAdd(&cnt[gid[i]], 1);
  __syncthreads();
  if (tid == 0) {
    int run = 0;
    for (int g = 0; g < NG; ++g) { goffs[g] = run; gcnt[g] = cnt[g]; run += cnt[g]; }
    goffs[NG] = run;
  }
}

// ---------- fp32 GEMM: C[M, 128*CPT] = A[M,128] @ BT[128, 128*CPT] (+bias) ----------
template <int CPT>
__global__ __launch_bounds__(256) void k_gemm128(const float* __restrict__ A,
    const float* __restrict__ BT, const float* __restrict__ bias,
    float* __restrict__ C, int M) {
  __shared__ float aT[D][17];
  const int NCc = D * CPT;
  int tid = threadIdx.x;
  int row0 = blockIdx.x * 16;
  for (int i = tid; i < 16 * D; i += 256) {
    int r = i >> 7, c = i & 127;
    int rr = row0 + r; if (rr >= M) rr = M - 1;
    aT[c][r] = A[(size_t)rr * D + c];
  }
  __syncthreads();
  int col = tid & 127, nh = tid >> 7;
  float acc[CPT][8];
  #pragma unroll
  for (int j = 0; j < CPT; ++j)
    #pragma unroll
    for (int n = 0; n < 8; ++n) acc[j][n] = 0.f;
  #pragma unroll 4
  for (int kk = 0; kk < D; ++kk) {
    float w[CPT];
    #pragma unroll
    for (int j = 0; j < CPT; ++j) w[j] = BT[kk * NCc + j * D + col];
    const float* ap = &aT[kk][nh * 8];
    #pragma unroll
    for (int n = 0; n < 8; ++n) {
      float av = ap[n];
      #pragma unroll
      for (int j = 0; j < CPT; ++j) acc[j][n] += w[j] * av;
    }
  }
  #pragma unroll
  for (int j = 0; j < CPT; ++j) {
    float b = bias ? bias[j * D + col] : 0.f;
    #pragma unroll
    for (int n = 0; n < 8; ++n) {
      int r = row0 + nh * 8 + n;
      if (r < M) C[(size_t)r * NCc + j * D + col] = acc[j][n] + b;
    }
  }
}

// ---------- message aggregate: a[n] = sum_{e: dst=n} t[src*4+etype] ----------
__global__ __launch_bounds__(256) void k_aggregate(const float* __restrict__ t,
    const int* __restrict__ row_ofs, const int* __restrict__ csr_row,
    float* __restrict__ a, int N) {
  int node = blockIdx.x * 4 + (threadIdx.x >> 6);
  int lane = threadIdx.x & 63;
  if (node >= N) return;
  int beg = row_ofs[node], end = row_ofs[node + 1];
  float ax = 0.f, ay = 0.f;
  for (int base = beg; base < end; base += 64) {
    int nv = end - base; if (nv > 64) nv = 64;
    int r = (lane < nv) ? csr_row[base + lane] : 0;
    for (int j = 0; j < nv; ++j) {
      int rr = __shfl(r, j);
      float2 v = ((const float2*)(t + (size_t)rr * D))[lane];
      ax += v.x; ay += v.y;
    }
  }
  float2 o; o.x = ax; o.y = ay;
  ((float2*)(a + (size_t)node * D))[lane] = o;
}

// ---------- fused GRU: h = GRU(a, h), 6 accumulators per thread ----------
__global__ __launch_bounds__(256) void k_gru(const float* __restrict__ a,
    float* __restrict__ h, const float* __restrict__ WihT,
    const float* __restrict__ WhhT, const float* __restrict__ b_ih,
    const float* __restrict__ b_hh, int M) {
  __shared__ float aT[D][17];
  __shared__ float hT[D][17];
  int tid = threadIdx.x;
  int row0 = blockIdx.x * 16;
  for (int i = tid; i < 16 * D; i += 256) {
    int r = i >> 7, c = i & 127;
    int rr = row0 + r; if (rr >= M) rr = M - 1;
    aT[c][r] = a[(size_t)rr * D + c];
    hT[c][r] = h[(size_t)rr * D + c];
  }
  __syncthreads();
  int col = tid & 127, nh = tid >> 7;
  float air[8] = {}, aiz[8] = {}, ain[8] = {};
  float ahr[8] = {}, ahz[8] = {}, ahn[8] = {};
  #pragma unroll 4
  for (int kk = 0; kk < D; ++kk) {
    float wr = WihT[kk * 384 + col];
    float wz = WihT[kk * 384 + 128 + col];
    float wn = WihT[kk * 384 + 256 + col];
    float ur = WhhT[kk * 384 + col];
    float uz = WhhT[kk * 384 + 128 + col];
    float un = WhhT[kk * 384 + 256 + col];
    const float* ap = &aT[kk][nh * 8];
    const float* hp = &hT[kk][nh * 8];
    #pragma unroll
    for (int n = 0; n < 8; ++n) {
      float av = ap[n], hv = hp[n];
      air[n] += wr * av; aiz[n] += wz * av; ain[n] += wn * av;
      ahr[n] += ur * hv; ahz[n] += uz * hv; ahn[n] += un * hv;
    }
  }
  float bir = b_ih[col], biz = b_ih[col + 128], bin_ = b_ih[col + 256];
  float bhr = b_hh[col], bhz = b_hh[col + 128], bhn = b_hh[col + 256];
  #pragma unroll
  for (int n = 0; n < 8; ++n) {
    int r = row0 + nh * 8 + n;
    if (r >= M) continue;
    float rg = sigf(air[n] + bir + ahr[n] + bhr);
    float zg = sigf(aiz[n] + biz + ahz[n] + bhz);
    float nng = tanhf(ain[n] + bin_ + rg * (ahn[n] + bhn));
    float hold = hT[col][nh * 8 + n];
    h[(size_t)r * D + col] = (1.f - zg) * nng + zg * hold;
  }
}

// ---------- L2 normalize (dim=1) + sigmoid, in place ----------
__global__ __launch_bounds__(256) void k_norm_sig(float* __restrict__ h, int N) {
  int node = blockIdx.x * 4 + (threadIdx.x >> 6);
  int lane = threadIdx.x & 63;
  if (node >= N) return;
  float2 v = ((float2*)(h + (size_t)node * D))[lane];
  float s = v.x * v.x + v.y * v.y;
  #pragma unroll
  for (int off = 32; off; off >>= 1) s += __shfl_xor(s, off);
  float inv = 1.f / fmaxf(sqrtf(s), 1e-12f);
  v.x = sigf(v.x * inv); v.y = sigf(v.y * inv);
  ((float2*)(h + (size_t)node * D))[lane] = v;
}

// ---------- el/er per node per head ----------
__global__ __launch_bounds__(256) void k_eler(const float* __restrict__ zft,
    const float* __restrict__ attn_l, const float* __restrict__ attn_r,
    float* __restrict__ el, float* __restrict__ er, int N) {
  int node = blockIdx.x * 4 + (threadIdx.x >> 6);
  int lane = threadIdx.x & 63;
  if (node >= N) return;
  float4 z = ((const float4*)(zft + (size_t)node * 256))[lane];
  float4 al = ((const float4*)attn_l)[lane];
  float4 ar = ((const float4*)attn_r)[lane];
  float pl = z.x * al.x + z.y * al.y + z.z * al.z + z.w * al.w;
  float pr = z.x * ar.x + z.y * ar.y + z.z * ar.z + z.w * ar.w;
  #pragma unroll
  for (int off = 16; off; off >>= 1) { pl += __shfl_xor(pl, off); pr += __shfl_xor(pr, off); }
  if ((lane & 31) == 0) {
    int hh = lane >> 5;
    el[node * 2 + hh] = pl;
    er[node * 2 + hh] = pr;
  }
}

// ---------- GAT aggregation (online softmax per dst node) ----------
__global__ __launch_bounds__(256) void k_gat(const float* __restrict__ zft,
    const float* __restrict__ el, const float* __restrict__ er,
    const int* __restrict__ row_ofs, const int* __restrict__ csr_src,
    const float* __restrict__ gat_bias, float* __restrict__ out, int N) {
  int node = blockIdx.x * 4 + (threadIdx.x >> 6);
  int lane = threadIdx.x & 63;
  if (node >= N) return;
  int beg = row_ofs[node], end = row_ofs[node + 1];
  float2 ern = ((const float2*)er)[node];
  float m0 = -INFINITY, m1 = -INFINITY, l0 = 0.f, l1 = 0.f;
  float4 acc = {0.f, 0.f, 0.f, 0.f};
  int head = lane >> 5;
  for (int base = beg; base < end; base += 64) {
    int nv = end - base; if (nv > 64) nv = 64;
    int sidx = (lane < nv) ? csr_src[base + lane] : 0;
    float e0 = -INFINITY, e1 = -INFINITY;
    if (lane < nv) {
      float2 els = ((const float2*)el)[sidx];
      e0 = lrelu(els.x + ern.x);
      e1 = lrelu(els.y + ern.y);
    }
    float c0 = e0, c1 = e1;
    #pragma unroll
    for (int off = 32; off; off >>= 1) {
      c0 = fmaxf(c0, __shfl_xor(c0, off));
      c1 = fmaxf(c1, __shfl_xor(c1, off));
    }
    float nm0 = fmaxf(m0, c0), nm1 = fmaxf(m1, c1);
    float s0 = expf(m0 - nm0), s1 = expf(m1 - nm1);
    float p0 = (lane < nv) ? expf(e0 - nm0) : 0.f;
    float p1 = (lane < nv) ? expf(e1 - nm1) : 0.f;
    float t0 = p0, t1 = p1;
    #pragma unroll
    for (int off = 32; off; off >>= 1) { t0 += __shfl_xor(t0, off); t1 += __shfl_xor(t1, off); }
    float sc = head ? s1 : s0;
    acc.x *= sc; acc.y *= sc; acc.z *= sc; acc.w *= sc;
    l0 = l0 * s0 + t0; l1 = l1 * s1 + t1;
    m0 = nm0; m1 = nm1;
    for (int j = 0; j < nv; ++j) {
      int sj = __shfl(sidx, j);
      float pj0 = __shfl(p0, j), pj1 = __shfl(p1, j);
      float w = head ? pj1 : pj0;
      float4 z = ((const float4*)(zft + (size_t)sj * 256))[lane];
      acc.x += w * z.x; acc.y += w * z.y; acc.z += w * z.z; acc.w += w * z.w;
    }
  }
  float inv0 = (l0 > 0.f) ? 1.f / l0 : 0.f;
  float inv1 = (l1 > 0.f) ? 1.f / l1 : 0.f;
  float inv = head ? inv1 : inv0;
  float4 b = ((const float4*)gat_bias)[lane];
  float4 o;
  o.x = fmaxf(acc.x * inv + b.x, 0.f);
  o.y = fmaxf(acc.y * inv + b.y, 0.f);
  o.z = fmaxf(acc.z * inv + b.z, 0.f);
  o.w = fmaxf(acc.w * inv + b.w, 0.f);
  ((float4*)(out + (size_t)node * 256))[lane] = o;
}

// ---------- per-graph sums (gid is sorted -> contiguous segments) ----------
__global__ __launch_bounds__(64) void k_segred(const float* __restrict__ hgat,
    const int* __restrict__ goffs, float* __restrict__ sums) {
  int g = blockIdx.x >> 2;
  int chunk = blockIdx.x & 3;
  int col = chunk * 64 + threadIdx.x;
  float acc = 0.f;
  int beg = goffs[g], end = goffs[g + 1];
  for (int i = beg; i < end; ++i) acc += hgat[(size_t)i * 256 + col];
  sums[g * 256 + col] = acc;
}

// ---------- mean + classifier: logits[g][h][c] ----------
__global__ __launch_bounds__(64) void k_classify(const float* __restrict__ sums,
    const int* __restrict__ gcnt, const float* __restrict__ W_cls,
    const float* __restrict__ b_cls, float* __restrict__ logits) {
  int g = blockIdx.x, tid = threadIdx.x;
  int hh = tid >> 5, c = tid & 31;
  float invc = 1.f / fmaxf((float)gcnt[g], 1.f);
  float acc = 0.f;
  for (int d = 0; d < D; ++d)
    acc += (sums[g * 256 + hh * D + d] * invc) * W_cls[c * D + d];
  logits[g * 64 + hh * 32 + c] = acc + b_cls[c];
}

// ---------- pairwise distance + softmax over heads ----------
__global__ __launch_bounds__(64) void k_final(const float* __restrict__ l1,
    const float* __restrict__ l2, float* __restrict__ out) {
  int g = threadIdx.x;
  if (g >= NG) return;
  float d[2];
  #pragma unroll
  for (int hh = 0; hh < 2; ++hh) {
    float s = 0.f;
    for (int c = 0; c < 32; ++c) {
      float df = l1[g * 64 + hh * 32 + c] - l2[g * 64 + hh * 32 + c] + 1e-6f;
      s += df * df;
    }
    d[hh] = sqrtf(s);
  }
  float mx = fmaxf(d[0], d[1]);
  float e0 = expf(d[0] - mx), e1 = expf(d[1] - mx);
  float den = e0 + e1;
  out[g * 2] = e0 / den;
  out[g * 2 + 1] = e1 / den;
}

extern "C" void kernel_launch(void* const* d_in, const int* in_sizes, int n_in,
                              void* d_out, int out_size, void* d_ws, size_t ws_size,
                              hipStream_t stream) {
  const float* in_feat[2] = {(const float*)d_in[0], (const float*)d_in[1]};
  const int* srcs[2] = {(const int*)d_in[2], (const int*)d_in[6]};
  const int* dsts[2] = {(const int*)d_in[3], (const int*)d_in[7]};
  const int* etys[2] = {(const int*)d_in[4], (const int*)d_in[8]};
  const int* gids[2] = {(const int*)d_in[5], (const int*)d_in[9]};
  const float* W_et = (const float*)d_in[10];
  const float* b_et = (const float*)d_in[11];
  const float* W_ih = (const float*)d_in[12];
  const float* W_hh = (const float*)d_in[13];
  const float* b_ih = (const float*)d_in[14];
  const float* b_hh = (const float*)d_in[15];
  const float* W_fc = (const float*)d_in[16];
  const float* attn_l = (const float*)d_in[17];
  const float* attn_r = (const float*)d_in[18];
  const float* gat_bias = (const float*)d_in[19];
  const float* W_cls = (const float*)d_in[20];
  const float* b_cls = (const float*)d_in[21];
  float* out = (float*)d_out;

  int N = in_sizes[0] / D;
  int E = in_sizes[2];

  char* p = (char*)d_ws;
  auto alloc = [&](size_t bytes) -> void* {
    char* r = p;
    p += (bytes + 255) & ~(size_t)255;
    return (void*)r;
  };
  float* wetT = (float*)alloc((size_t)512 * 128 * 4);
  float* wihT = (float*)alloc((size_t)384 * 128 * 4);
  float* whhT = (float*)alloc((size_t)384 * 128 * 4);
  float* wfcT = (float*)alloc((size_t)256 * 128 * 4);
  float* h = (float*)alloc((size_t)N * D * 4);
  float* a = (float*)alloc((size_t)N * D * 4);
  float* t = (float*)alloc((size_t)N * 512 * 4);
  float* el = (float*)alloc((size_t)N * 2 * 4);
  float* er = (float*)alloc((size_t)N * 2 * 4);
  float* sums = (float*)alloc((size_t)NG * 256 * 4);
  float* logits0 = (float*)alloc((size_t)NG * 64 * 4);
  float* logits1 = (float*)alloc((size_t)NG * 64 * 4);
  int* deg = (int*)alloc((size_t)N * 4);
  int* row_ofs = (int*)alloc(((size_t)N + 1) * 4);
  int* cursor = (int*)alloc((size_t)N * 4);
  int* csr_src = (int*)alloc((size_t)E * 4);
  int* csr_row = (int*)alloc((size_t)E * 4);
  int* goffs = (int*)alloc((size_t)65 * 4);
  int* gcnt = (int*)alloc((size_t)64 * 4);
  if ((size_t)(p - (char*)d_ws) > ws_size) return;  // workspace too small: bail loudly

  float* zft = t;                       // [N,256] reuse of t
  float* hgat = t + (size_t)N * 256;    // [N,256] reuse of t (2nd half)
  float* logits[2] = {logits0, logits1};

  k_transpose<<<dim3(256), dim3(256), 0, stream>>>(W_et, wetT, 512, 128);
  k_transpose<<<dim3(192), dim3(256), 0, stream>>>(W_ih, wihT, 384, 128);
  k_transpose<<<dim3(192), dim3(256), 0, stream>>>(W_hh, whhT, 384, 128);
  k_transpose<<<dim3(128), dim3(256), 0, stream>>>(W_fc, wfcT, 256, 128);

  int gb = (N + 15) / 16;
  int nb4 = (N + 3) / 4;
  int eb = (E + 255) / 256;

  for (int gi = 0; gi < 2; ++gi) {
    hipMemsetAsync(deg, 0, (size_t)N * 4, stream);
    k_hist<<<dim3(eb), dim3(256), 0, stream>>>(dsts[gi], E, deg);
    k_scan<<<dim3(1), dim3(1024), 0, stream>>>(deg, row_ofs, cursor, N);
    k_scatter<<<dim3(eb), dim3(256), 0, stream>>>(srcs[gi], dsts[gi], etys[gi], E,
                                                  cursor, csr_src, csr_row);
    k_goffs<<<dim3(1), dim3(256), 0, stream>>>(gids[gi], N, goffs, gcnt);
    hipMemcpyAsync(h, in_feat[gi], (size_t)N * D * 4, hipMemcpyDeviceToDevice, stream);
    for (int s = 0; s < NSTEPS; ++s) {
      k_gemm128<4><<<dim3(gb), dim3(256), 0, stream>>>(h, wetT, b_et, t, N);
      k_aggregate<<<dim3(nb4), dim3(256), 0, stream>>>(t, row_ofs, csr_row, a, N);
      k_gru<<<dim3(gb), dim3(256), 0, stream>>>(a, h, wihT, whhT, b_ih, b_hh, N);
    }
    k_norm_sig<<<dim3(nb4), dim3(256), 0, stream>>>(h, N);
    k_gemm128<2><<<dim3(gb), dim3(256), 0, stream>>>(h, wfcT, nullptr, zft, N);
    k_eler<<<dim3(nb4), dim3(256), 0, stream>>>(zft, attn_l, attn_r, el, er, N);
    k_gat<<<dim3(nb4), dim3(256), 0, stream>>>(zft, el, er, row_ofs, csr_src,
                                               gat_bias, hgat, N);
    k_segred<<<dim3(NG * 4), dim3(64), 0, stream>>>(hgat, goffs, sums);
    k_classify<<<dim3(NG), dim3(64), 0, stream>>>(sums, gcnt, W_cls, b_cls, logits[gi]);
  }
  k_final<<<dim3(1), dim3(64), 0, stream>>>(logits[0], logits[1], out);
}

// Round 2
// 2628.209 us; speedup vs baseline: 1.8302x; 1.8302x over previous
//
#include <hip/hip_runtime.h>
#include <math.h>

#define D 128
#define NG 64
#define NSTEPS 5

using short8 = __attribute__((ext_vector_type(8))) short;
using f32x4  = __attribute__((ext_vector_type(4))) float;

__device__ __forceinline__ float sigf(float x) { return 1.f / (1.f + expf(-x)); }
__device__ __forceinline__ float lrelu(float x) { return x > 0.f ? x : 0.2f * x; }
__device__ __forceinline__ short f2bf(float x) {
  unsigned u = __float_as_uint(x);
  u += 0x7fff + ((u >> 16) & 1);
  return (short)(u >> 16);
}

// ---------- fp32 -> bf16 bulk convert (n divisible by 4) ----------
__global__ void k_cvt(const float* __restrict__ in, short* __restrict__ out, int n4) {
  for (int i = blockIdx.x * blockDim.x + threadIdx.x; i < n4; i += gridDim.x * blockDim.x) {
    float4 v = ((const float4*)in)[i];
    short s0 = f2bf(v.x), s1 = f2bf(v.y), s2 = f2bf(v.z), s3 = f2bf(v.w);
    unsigned lo = ((unsigned)(unsigned short)s1 << 16) | (unsigned short)s0;
    unsigned hi = ((unsigned)(unsigned short)s3 << 16) | (unsigned short)s2;
    ((uint2*)out)[i] = make_uint2(lo, hi);
  }
}

// ---------- pack W[NC][128] (fp32, row-major out x in) into MFMA b-frag order ----------
// P[((nt*4+kt)*64+lane)*8+j] = bf16( W[(nt*16+(lane&15))*128 + kt*32 + (lane>>4)*8 + j] )
__global__ void k_pack(const float* __restrict__ W, short* __restrict__ P, int NC) {
  int n = NC * 128;
  for (int i = blockIdx.x * blockDim.x + threadIdx.x; i < n; i += gridDim.x * blockDim.x) {
    int j = i & 7;
    int lane = (i >> 3) & 63;
    int kt = (i >> 9) & 3;
    int nt = i >> 11;
    int c = nt * 16 + (lane & 15);
    int k = kt * 32 + ((lane >> 4) << 3) + j;
    P[i] = f2bf(W[c * 128 + k]);
  }
}

// ---------- CSR build ----------
__global__ void k_hist(const int* __restrict__ dst, int E, int* __restrict__ deg) {
  for (int e = blockIdx.x * blockDim.x + threadIdx.x; e < E; e += gridDim.x * blockDim.x)
    atomicAdd(&deg[dst[e]], 1);
}

__global__ __launch_bounds__(1024) void k_scan(const int* __restrict__ deg,
    int* __restrict__ row_ofs, int* __restrict__ cursor, int N) {
  int tid = threadIdx.x;
  int per = (N + 1023) / 1024;
  int beg = tid * per, end = beg + per; if (end > N) end = N; if (beg > N) beg = N;
  int s = 0;
  for (int i = beg; i < end; ++i) s += deg[i];
  int lane = tid & 63, wv = tid >> 6;
  int x = s;
  #pragma unroll
  for (int off = 1; off < 64; off <<= 1) {
    int y = __shfl_up(x, off);
    if (lane >= off) x += y;
  }
  __shared__ int wsum[16];
  if (lane == 63) wsum[wv] = x;
  __syncthreads();
  if (tid < 16) {
    int v = wsum[tid];
    #pragma unroll
    for (int off = 1; off < 16; off <<= 1) {
      int y = __shfl_up(v, off);
      if (tid >= off) v += y;
    }
    wsum[tid] = v;
  }
  __syncthreads();
  int woff = (wv > 0) ? wsum[wv - 1] : 0;
  int run = woff + x - s;  // exclusive prefix of this thread's chunk
  for (int i = beg; i < end; ++i) {
    int d = deg[i];
    cursor[i] = run;
    run += d;
    row_ofs[i + 1] = run;
  }
  if (tid == 0) row_ofs[0] = 0;
}

__global__ void k_scatter(const int* __restrict__ src, const int* __restrict__ dst,
                          const int* __restrict__ ety, int E, int* __restrict__ cursor,
                          int* __restrict__ csr_src, int* __restrict__ csr_row) {
  for (int e = blockIdx.x * blockDim.x + threadIdx.x; e < E; e += gridDim.x * blockDim.x) {
    int p = atomicAdd(&cursor[dst[e]], 1);
    int s = src[e];
    csr_src[p] = s;
    csr_row[p] = s * 4 + ety[e];
  }
}

__global__ void k_goffs(const int* __restrict__ gid, int N,
                        int* __restrict__ goffs, int* __restrict__ gcnt) {
  __shared__ int cnt[NG];
  int tid = threadIdx.x;
  if (tid < NG) cnt[tid] = 0;
  __syncthreads();
  for (int i = tid; i < N; i += blockDim.x) atomicAdd(&cnt[gid[i]], 1);
  __syncthreads();
  if (tid == 0) {
    int run = 0;
    for (int g = 0; g < NG; ++g) { goffs[g] = run; gcnt[g] = cnt[g]; run += cnt[g]; }
    goffs[NG] = run;
  }
}

// ---------- MFMA GEMM: C[M, NT*16] = A_bf16[M,128] @ Bpacked (+bias) ----------
template <int NT, bool OUT_BF16>
__global__ __launch_bounds__(256) void k_mfma_gemm(const short* __restrict__ Ab,
    const short* __restrict__ Bp, const float* __restrict__ bias,
    void* __restrict__ Cout, int M) {
  int tid = threadIdx.x;
  int lane = tid & 63, wave = tid >> 6;
  int row0 = blockIdx.x * 64 + wave * 16;
  int quad = lane >> 4, l15 = lane & 15;
  int ar = row0 + l15; if (ar >= M) ar = M - 1;
  short8 af[4];
  #pragma unroll
  for (int kt = 0; kt < 4; ++kt)
    af[kt] = *(const short8*)(Ab + (size_t)ar * 128 + kt * 32 + quad * 8);
  const int NCc = NT * 16;
  for (int nt = 0; nt < NT; ++nt) {
    f32x4 acc = {0.f, 0.f, 0.f, 0.f};
    #pragma unroll
    for (int kt = 0; kt < 4; ++kt) {
      short8 b = *(const short8*)(Bp + (((size_t)(nt * 4 + kt) * 64) + lane) * 8);
      acc = __builtin_amdgcn_mfma_f32_16x16x32_bf16(af[kt], b, acc, 0, 0, 0);
    }
    int c = nt * 16 + l15;
    float bv = bias ? bias[c] : 0.f;
    #pragma unroll
    for (int reg = 0; reg < 4; ++reg) {
      int r = row0 + quad * 4 + reg;
      if (r < M) {
        float v = acc[reg] + bv;
        if (OUT_BF16) ((short*)Cout)[(size_t)r * NCc + c] = f2bf(v);
        else ((float*)Cout)[(size_t)r * NCc + c] = v;
      }
    }
  }
}

// ---------- message aggregate (bf16 t): a[n] = sum_{e: dst=n} t[src*4+etype] ----------
__global__ __launch_bounds__(256) void k_aggregate(const short* __restrict__ t,
    const int* __restrict__ row_ofs, const int* __restrict__ csr_row,
    short* __restrict__ ab, int N) {
  int node = blockIdx.x * 4 + (threadIdx.x >> 6);
  int lane = threadIdx.x & 63;
  if (node >= N) return;
  int beg = row_ofs[node], end = row_ofs[node + 1];
  float ax = 0.f, ay = 0.f;
  for (int base = beg; base < end; base += 64) {
    int nv = end - base; if (nv > 64) nv = 64;
    int r = (lane < nv) ? csr_row[base + lane] : 0;
    for (int j = 0; j < nv; ++j) {
      int rr = __shfl(r, j);
      unsigned v = ((const unsigned*)(t + (size_t)rr * 128))[lane];
      ax += __uint_as_float(v << 16);
      ay += __uint_as_float(v & 0xffff0000u);
    }
  }
  unsigned o = ((unsigned)(unsigned short)f2bf(ay) << 16) | (unsigned short)f2bf(ax);
  ((unsigned*)(ab + (size_t)node * 128))[lane] = o;
}

// ---------- fused GRU via MFMA: h = GRU(a, h) ----------
__global__ __launch_bounds__(256) void k_gru_mfma(const short* __restrict__ ab,
    short* __restrict__ hb, float* __restrict__ hf,
    const short* __restrict__ Pih, const short* __restrict__ Phh,
    const float* __restrict__ b_ih, const float* __restrict__ b_hh, int M) {
  int tid = threadIdx.x;
  int lane = tid & 63, wave = tid >> 6;
  int row0 = blockIdx.x * 64 + wave * 16;
  int quad = lane >> 4, l15 = lane & 15;
  int ar = row0 + l15; if (ar >= M) ar = M - 1;
  short8 fa[4], fh[4];
  #pragma unroll
  for (int kt = 0; kt < 4; ++kt) {
    fa[kt] = *(const short8*)(ab + (size_t)ar * 128 + kt * 32 + quad * 8);
    fh[kt] = *(const short8*)(hb + (size_t)ar * 128 + kt * 32 + quad * 8);
  }
  for (int nt = 0; nt < 8; ++nt) {
    f32x4 accr = {0.f,0.f,0.f,0.f}, accz = {0.f,0.f,0.f,0.f};
    f32x4 acci = {0.f,0.f,0.f,0.f}, acch = {0.f,0.f,0.f,0.f};
    #pragma unroll
    for (int kt = 0; kt < 4; ++kt) {
      size_t li = ((size_t)lane) * 8;
      short8 wr = *(const short8*)(Pih + ((size_t)((nt     ) * 4 + kt) * 64) * 8 + li);
      short8 wz = *(const short8*)(Pih + ((size_t)((nt +  8) * 4 + kt) * 64) * 8 + li);
      short8 wn = *(const short8*)(Pih + ((size_t)((nt + 16) * 4 + kt) * 64) * 8 + li);
      short8 ur = *(const short8*)(Phh + ((size_t)((nt     ) * 4 + kt) * 64) * 8 + li);
      short8 uz = *(const short8*)(Phh + ((size_t)((nt +  8) * 4 + kt) * 64) * 8 + li);
      short8 un = *(const short8*)(Phh + ((size_t)((nt + 16) * 4 + kt) * 64) * 8 + li);
      accr = __builtin_amdgcn_mfma_f32_16x16x32_bf16(fa[kt], wr, accr, 0, 0, 0);
      accr = __builtin_amdgcn_mfma_f32_16x16x32_bf16(fh[kt], ur, accr, 0, 0, 0);
      accz = __builtin_amdgcn_mfma_f32_16x16x32_bf16(fa[kt], wz, accz, 0, 0, 0);
      accz = __builtin_amdgcn_mfma_f32_16x16x32_bf16(fh[kt], uz, accz, 0, 0, 0);
      acci = __builtin_amdgcn_mfma_f32_16x16x32_bf16(fa[kt], wn, acci, 0, 0, 0);
      acch = __builtin_amdgcn_mfma_f32_16x16x32_bf16(fh[kt], un, acch, 0, 0, 0);
    }
    int c = nt * 16 + l15;
    float bir = b_ih[c],      bhr = b_hh[c];
    float biz = b_ih[c+128],  bhz = b_hh[c+128];
    float bin_= b_ih[c+256],  bhn = b_hh[c+256];
    #pragma unroll
    for (int reg = 0; reg < 4; ++reg) {
      int r = row0 + quad * 4 + reg;
      if (r < M) {
        float rg = sigf(accr[reg] + bir + bhr);
        float zg = sigf(accz[reg] + biz + bhz);
        float ng = tanhf(acci[reg] + bin_ + rg * (acch[reg] + bhn));
        float hold = hf[(size_t)r * 128 + c];
        float hn2 = (1.f - zg) * ng + zg * hold;
        hf[(size_t)r * 128 + c] = hn2;
        hb[(size_t)r * 128 + c] = f2bf(hn2);
      }
    }
  }
}

// ---------- L2 normalize + sigmoid: hf (fp32) -> hb (bf16) ----------
__global__ __launch_bounds__(256) void k_norm_sig(const float* __restrict__ hf,
    short* __restrict__ hb, int N) {
  int node = blockIdx.x * 4 + (threadIdx.x >> 6);
  int lane = threadIdx.x & 63;
  if (node >= N) return;
  float2 v = ((const float2*)(hf + (size_t)node * D))[lane];
  float s = v.x * v.x + v.y * v.y;
  #pragma unroll
  for (int off = 32; off; off >>= 1) s += __shfl_xor(s, off);
  float inv = 1.f / fmaxf(sqrtf(s), 1e-12f);
  float x = sigf(v.x * inv), y = sigf(v.y * inv);
  unsigned o = ((unsigned)(unsigned short)f2bf(y) << 16) | (unsigned short)f2bf(x);
  ((unsigned*)(hb + (size_t)node * D))[lane] = o;
}

// ---------- el/er per node per head ----------
__global__ __launch_bounds__(256) void k_eler(const float* __restrict__ zft,
    const float* __restrict__ attn_l, const float* __restrict__ attn_r,
    float* __restrict__ el, float* __restrict__ er, int N) {
  int node = blockIdx.x * 4 + (threadIdx.x >> 6);
  int lane = threadIdx.x & 63;
  if (node >= N) return;
  float4 z = ((const float4*)(zft + (size_t)node * 256))[lane];
  float4 al = ((const float4*)attn_l)[lane];
  float4 ar = ((const float4*)attn_r)[lane];
  float pl = z.x * al.x + z.y * al.y + z.z * al.z + z.w * al.w;
  float pr = z.x * ar.x + z.y * ar.y + z.z * ar.z + z.w * ar.w;
  #pragma unroll
  for (int off = 16; off; off >>= 1) { pl += __shfl_xor(pl, off); pr += __shfl_xor(pr, off); }
  if ((lane & 31) == 0) {
    int hh = lane >> 5;
    el[node * 2 + hh] = pl;
    er[node * 2 + hh] = pr;
  }
}

// ---------- GAT aggregation (online softmax per dst node) ----------
__global__ __launch_bounds__(256) void k_gat(const float* __restrict__ zft,
    const float* __restrict__ el, const float* __restrict__ er,
    const int* __restrict__ row_ofs, const int* __restrict__ csr_src,
    const float* __restrict__ gat_bias, float* __restrict__ out, int N) {
  int node = blockIdx.x * 4 + (threadIdx.x >> 6);
  int lane = threadIdx.x & 63;
  if (node >= N) return;
  int beg = row_ofs[node], end = row_ofs[node + 1];
  float2 ern = ((const float2*)er)[node];
  float m0 = -INFINITY, m1 = -INFINITY, l0 = 0.f, l1 = 0.f;
  float4 acc = {0.f, 0.f, 0.f, 0.f};
  int head = lane >> 5;
  for (int base = beg; base < end; base += 64) {
    int nv = end - base; if (nv > 64) nv = 64;
    int sidx = (lane < nv) ? csr_src[base + lane] : 0;
    float e0 = -INFINITY, e1 = -INFINITY;
    if (lane < nv) {
      float2 els = ((const float2*)el)[sidx];
      e0 = lrelu(els.x + ern.x);
      e1 = lrelu(els.y + ern.y);
    }
    float c0 = e0, c1 = e1;
    #pragma unroll
    for (int off = 32; off; off >>= 1) {
      c0 = fmaxf(c0, __shfl_xor(c0, off));
      c1 = fmaxf(c1, __shfl_xor(c1, off));
    }
    float nm0 = fmaxf(m0, c0), nm1 = fmaxf(m1, c1);
    float s0 = expf(m0 - nm0), s1 = expf(m1 - nm1);
    float p0 = (lane < nv) ? expf(e0 - nm0) : 0.f;
    float p1 = (lane < nv) ? expf(e1 - nm1) : 0.f;
    float t0 = p0, t1 = p1;
    #pragma unroll
    for (int off = 32; off; off >>= 1) { t0 += __shfl_xor(t0, off); t1 += __shfl_xor(t1, off); }
    float sc = head ? s1 : s0;
    acc.x *= sc; acc.y *= sc; acc.z *= sc; acc.w *= sc;
    l0 = l0 * s0 + t0; l1 = l1 * s1 + t1;
    m0 = nm0; m1 = nm1;
    for (int j = 0; j < nv; ++j) {
      int sj = __shfl(sidx, j);
      float pj0 = __shfl(p0, j), pj1 = __shfl(p1, j);
      float w = head ? pj1 : pj0;
      float4 z = ((const float4*)(zft + (size_t)sj * 256))[lane];
      acc.x += w * z.x; acc.y += w * z.y; acc.z += w * z.z; acc.w += w * z.w;
    }
  }
  float inv0 = (l0 > 0.f) ? 1.f / l0 : 0.f;
  float inv1 = (l1 > 0.f) ? 1.f / l1 : 0.f;
  float inv = head ? inv1 : inv0;
  float4 b = ((const float4*)gat_bias)[lane];
  float4 o;
  o.x = fmaxf(acc.x * inv + b.x, 0.f);
  o.y = fmaxf(acc.y * inv + b.y, 0.f);
  o.z = fmaxf(acc.z * inv + b.z, 0.f);
  o.w = fmaxf(acc.w * inv + b.w, 0.f);
  ((float4*)(out + (size_t)node * 256))[lane] = o;
}

// ---------- per-graph sums (gid sorted -> contiguous segments) ----------
__global__ __launch_bounds__(64) void k_segred(const float* __restrict__ hgat,
    const int* __restrict__ goffs, float* __restrict__ sums) {
  int g = blockIdx.x >> 2;
  int chunk = blockIdx.x & 3;
  int col = chunk * 64 + threadIdx.x;
  float acc = 0.f;
  int beg = goffs[g], end = goffs[g + 1];
  for (int i = beg; i < end; ++i) acc += hgat[(size_t)i * 256 + col];
  sums[g * 256 + col] = acc;
}

// ---------- mean + classifier ----------
__global__ __launch_bounds__(64) void k_classify(const float* __restrict__ sums,
    const int* __restrict__ gcnt, const float* __restrict__ W_cls,
    const float* __restrict__ b_cls, float* __restrict__ logits) {
  int g = blockIdx.x, tid = threadIdx.x;
  int hh = tid >> 5, c = tid & 31;
  float invc = 1.f / fmaxf((float)gcnt[g], 1.f);
  float acc = 0.f;
  for (int d = 0; d < D; ++d)
    acc += (sums[g * 256 + hh * D + d] * invc) * W_cls[c * D + d];
  logits[g * 64 + hh * 32 + c] = acc + b_cls[c];
}

// ---------- pairwise distance + softmax over heads ----------
__global__ __launch_bounds__(64) void k_final(const float* __restrict__ l1,
    const float* __restrict__ l2, float* __restrict__ out) {
  int g = threadIdx.x;
  if (g >= NG) return;
  float d[2];
  #pragma unroll
  for (int hh = 0; hh < 2; ++hh) {
    float s = 0.f;
    for (int c = 0; c < 32; ++c) {
      float df = l1[g * 64 + hh * 32 + c] - l2[g * 64 + hh * 32 + c] + 1e-6f;
      s += df * df;
    }
    d[hh] = sqrtf(s);
  }
  float mx = fmaxf(d[0], d[1]);
  float e0 = expf(d[0] - mx), e1 = expf(d[1] - mx);
  float den = e0 + e1;
  out[g * 2] = e0 / den;
  out[g * 2 + 1] = e1 / den;
}

extern "C" void kernel_launch(void* const* d_in, const int* in_sizes, int n_in,
                              void* d_out, int out_size, void* d_ws, size_t ws_size,
                              hipStream_t stream) {
  const float* in_feat[2] = {(const float*)d_in[0], (const float*)d_in[1]};
  const int* srcs[2] = {(const int*)d_in[2], (const int*)d_in[6]};
  const int* dsts[2] = {(const int*)d_in[3], (const int*)d_in[7]};
  const int* etys[2] = {(const int*)d_in[4], (const int*)d_in[8]};
  const int* gids[2] = {(const int*)d_in[5], (const int*)d_in[9]};
  const float* W_et = (const float*)d_in[10];
  const float* b_et = (const float*)d_in[11];
  const float* W_ih = (const float*)d_in[12];
  const float* W_hh = (const float*)d_in[13];
  const float* b_ih = (const float*)d_in[14];
  const float* b_hh = (const float*)d_in[15];
  const float* W_fc = (const float*)d_in[16];
  const float* attn_l = (const float*)d_in[17];
  const float* attn_r = (const float*)d_in[18];
  const float* gat_bias = (const float*)d_in[19];
  const float* W_cls = (const float*)d_in[20];
  const float* b_cls = (const float*)d_in[21];
  float* out = (float*)d_out;

  int N = in_sizes[0] / D;
  int E = in_sizes[2];

  char* p = (char*)d_ws;
  auto alloc = [&](size_t bytes) -> void* {
    char* r = p;
    p += (bytes + 255) & ~(size_t)255;
    return (void*)r;
  };
  short* WetP = (short*)alloc((size_t)512 * 128 * 2);
  short* WihP = (short*)alloc((size_t)384 * 128 * 2);
  short* WhhP = (short*)alloc((size_t)384 * 128 * 2);
  short* WfcP = (short*)alloc((size_t)256 * 128 * 2);
  float* hf  = (float*)alloc((size_t)N * D * 4);
  short* hb  = (short*)alloc((size_t)N * D * 2);
  short* ab  = (short*)alloc((size_t)N * D * 2);
  short* t   = (short*)alloc((size_t)N * 512 * 2);   // bf16 messages [N*4,128]
  float* zft = (float*)alloc((size_t)N * 256 * 4);
  float* hgat= (float*)alloc((size_t)N * 256 * 4);
  float* el  = (float*)alloc((size_t)N * 2 * 4);
  float* er  = (float*)alloc((size_t)N * 2 * 4);
  float* sums= (float*)alloc((size_t)NG * 256 * 4);
  float* logits0 = (float*)alloc((size_t)NG * 64 * 4);
  float* logits1 = (float*)alloc((size_t)NG * 64 * 4);
  int* deg     = (int*)alloc((size_t)N * 4);
  int* row_ofs = (int*)alloc(((size_t)N + 1) * 4);
  int* cursor  = (int*)alloc((size_t)N * 4);
  int* csr_src = (int*)alloc((size_t)E * 4);
  int* csr_row = (int*)alloc((size_t)E * 4);
  int* goffs   = (int*)alloc((size_t)65 * 4);
  int* gcnt    = (int*)alloc((size_t)64 * 4);
  if ((size_t)(p - (char*)d_ws) > ws_size) return;

  float* logits[2] = {logits0, logits1};

  // weight packing (cheap; runs every call to keep graph-capture legal)
  k_pack<<<dim3(64), dim3(256), 0, stream>>>(W_et, WetP, 512);
  k_pack<<<dim3(48), dim3(256), 0, stream>>>(W_ih, WihP, 384);
  k_pack<<<dim3(48), dim3(256), 0, stream>>>(W_hh, WhhP, 384);
  k_pack<<<dim3(32), dim3(256), 0, stream>>>(W_fc, WfcP, 256);

  int gb64 = (N + 63) / 64;
  int nb4 = (N + 3) / 4;
  int eb = (E + 255) / 256;

  for (int gi = 0; gi < 2; ++gi) {
    hipMemsetAsync(deg, 0, (size_t)N * 4, stream);
    k_hist<<<dim3(eb), dim3(256), 0, stream>>>(dsts[gi], E, deg);
    k_scan<<<dim3(1), dim3(1024), 0, stream>>>(deg, row_ofs, cursor, N);
    k_scatter<<<dim3(eb), dim3(256), 0, stream>>>(srcs[gi], dsts[gi], etys[gi], E,
                                                  cursor, csr_src, csr_row);
    k_goffs<<<dim3(1), dim3(256), 0, stream>>>(gids[gi], N, goffs, gcnt);
    hipMemcpyAsync(hf, in_feat[gi], (size_t)N * D * 4, hipMemcpyDeviceToDevice, stream);
    k_cvt<<<dim3(512), dim3(256), 0, stream>>>(in_feat[gi], hb, N * D / 4);
    for (int s = 0; s < NSTEPS; ++s) {
      k_mfma_gemm<32, true><<<dim3(gb64), dim3(256), 0, stream>>>(hb, WetP, b_et, t, N);
      k_aggregate<<<dim3(nb4), dim3(256), 0, stream>>>(t, row_ofs, csr_row, ab, N);
      k_gru_mfma<<<dim3(gb64), dim3(256), 0, stream>>>(ab, hb, hf, WihP, WhhP,
                                                       b_ih, b_hh, N);
    }
    k_norm_sig<<<dim3(nb4), dim3(256), 0, stream>>>(hf, hb, N);
    k_mfma_gemm<16, false><<<dim3(gb64), dim3(256), 0, stream>>>(hb, WfcP, nullptr, zft, N);
    k_eler<<<dim3(nb4), dim3(256), 0, stream>>>(zft, attn_l, attn_r, el, er, N);
    k_gat<<<dim3(nb4), dim3(256), 0, stream>>>(zft, el, er, row_ofs, csr_src,
                                               gat_bias, hgat, N);
    k_segred<<<dim3(NG * 4), dim3(64), 0, stream>>>(hgat, goffs, sums);
    k_classify<<<dim3(NG), dim3(64), 0, stream>>>(sums, gcnt, W_cls, b_cls, logits[gi]);
  }
  k_final<<<dim3(1), dim3(64), 0, stream>>>(logits[0], logits[1], out);
}

// Round 3
// 1934.843 us; speedup vs baseline: 2.4860x; 1.3584x over previous
//
#include <hip/hip_runtime.h>
#include <math.h>

#define D 128
#define NG 64
#define NG2 128
#define NSTEPS 5

using short8 = __attribute__((ext_vector_type(8))) short;
using f32x4  = __attribute__((ext_vector_type(4))) float;

__device__ __forceinline__ float sigf(float x) { return 1.f / (1.f + expf(-x)); }
__device__ __forceinline__ float lrelu(float x) { return x > 0.f ? x : 0.2f * x; }
__device__ __forceinline__ short f2bf(float x) {
  unsigned u = __float_as_uint(x);
  u += 0x7fff + ((u >> 16) & 1);
  return (short)(u >> 16);
}
__device__ __forceinline__ float bflo(unsigned v) { return __uint_as_float(v << 16); }
__device__ __forceinline__ float bfhi(unsigned v) { return __uint_as_float(v & 0xffff0000u); }

// ---------- fp32 -> bf16 bulk convert ----------
__global__ void k_cvt(const float* __restrict__ in, short* __restrict__ out, int n4) {
  for (int i = blockIdx.x * blockDim.x + threadIdx.x; i < n4; i += gridDim.x * blockDim.x) {
    float4 v = ((const float4*)in)[i];
    unsigned lo = ((unsigned)(unsigned short)f2bf(v.y) << 16) | (unsigned short)f2bf(v.x);
    unsigned hi = ((unsigned)(unsigned short)f2bf(v.w) << 16) | (unsigned short)f2bf(v.z);
    ((uint2*)out)[i] = make_uint2(lo, hi);
  }
}

// ---------- pack W[NC][128] into MFMA b-frag order ----------
__global__ void k_pack(const float* __restrict__ W, short* __restrict__ P, int NC) {
  int n = NC * 128;
  for (int i = blockIdx.x * blockDim.x + threadIdx.x; i < n; i += gridDim.x * blockDim.x) {
    int j = i & 7;
    int lane = (i >> 3) & 63;
    int kt = (i >> 9) & 3;
    int nt = i >> 11;
    int c = nt * 16 + (lane & 15);
    int k = kt * 32 + ((lane >> 4) << 3) + j;
    P[i] = f2bf(W[c * 128 + k]);
  }
}

// ---------- CSR build over merged graph (2 edge lists, node offset N) ----------
__global__ void k_hist(const int* __restrict__ dst1, const int* __restrict__ dst2,
                       int E, int N, int* __restrict__ deg) {
  for (int e = blockIdx.x * blockDim.x + threadIdx.x; e < 2 * E; e += gridDim.x * blockDim.x) {
    int d = (e < E) ? dst1[e] : dst2[e - E] + N;
    atomicAdd(&deg[d], 1);
  }
}

__global__ __launch_bounds__(1024) void k_scan(const int* __restrict__ deg,
    int* __restrict__ row_ofs, int* __restrict__ cursor, int N) {
  int tid = threadIdx.x;
  int per = (N + 1023) / 1024;
  int beg = tid * per, end = beg + per; if (end > N) end = N; if (beg > N) beg = N;
  int s = 0;
  for (int i = beg; i < end; ++i) s += deg[i];
  int lane = tid & 63, wv = tid >> 6;
  int x = s;
  #pragma unroll
  for (int off = 1; off < 64; off <<= 1) {
    int y = __shfl_up(x, off);
    if (lane >= off) x += y;
  }
  __shared__ int wsum[16];
  if (lane == 63) wsum[wv] = x;
  __syncthreads();
  if (tid < 16) {
    int v = wsum[tid];
    #pragma unroll
    for (int off = 1; off < 16; off <<= 1) {
      int y = __shfl_up(v, off);
      if (tid >= off) v += y;
    }
    wsum[tid] = v;
  }
  __syncthreads();
  int woff = (wv > 0) ? wsum[wv - 1] : 0;
  int run = woff + x - s;
  for (int i = beg; i < end; ++i) {
    int d = deg[i];
    cursor[i] = run;
    run += d;
    row_ofs[i + 1] = run;
  }
  if (tid == 0) row_ofs[0] = 0;
}

__global__ void k_scatter(const int* __restrict__ src1, const int* __restrict__ dst1,
                          const int* __restrict__ ety1, const int* __restrict__ src2,
                          const int* __restrict__ dst2, const int* __restrict__ ety2,
                          int E, int N, int* __restrict__ cursor,
                          int* __restrict__ csr_src, int* __restrict__ csr_row) {
  for (int e = blockIdx.x * blockDim.x + threadIdx.x; e < 2 * E; e += gridDim.x * blockDim.x) {
    int s, d, et;
    if (e < E) { s = src1[e]; d = dst1[e]; et = ety1[e]; }
    else { s = src2[e - E] + N; d = dst2[e - E] + N; et = ety2[e - E]; }
    int p = atomicAdd(&cursor[d], 1);
    csr_src[p] = s;
    csr_row[p] = s * 4 + et;
  }
}

// ---------- merged gid array [2N] + per-graph counts [128] ----------
__global__ void k_fillgid(const int* __restrict__ gid1, const int* __restrict__ gid2,
                          int N, int* __restrict__ gidc, int* __restrict__ gcnt) {
  __shared__ int cnt[NG2];
  int t = threadIdx.x;
  if (t < NG2) cnt[t] = 0;
  __syncthreads();
  int i = blockIdx.x * 256 + t;
  if (i < 2 * N) {
    int g = (i < N) ? gid1[i] : gid2[i - N] + NG;
    gidc[i] = g;
    atomicAdd(&cnt[g], 1);
  }
  __syncthreads();
  if (t < NG2 && cnt[t]) atomicAdd(&gcnt[t], cnt[t]);
}

// ---------- MFMA GEMM, 32 rows/wave: C[M, NT*16] = A_bf16[M,128] @ Bp (+bias) ----------
template <int NT, bool OUT_BF16>
__global__ __launch_bounds__(256) void k_mfma_gemm(const short* __restrict__ Ab,
    const short* __restrict__ Bp, const float* __restrict__ bias,
    void* __restrict__ Cout, int M) {
  int tid = threadIdx.x;
  int lane = tid & 63, wave = tid >> 6;
  int row0 = blockIdx.x * 128 + wave * 32;
  int quad = lane >> 4, l15 = lane & 15;
  short8 af[2][4];
  #pragma unroll
  for (int rt = 0; rt < 2; ++rt) {
    int ar = row0 + rt * 16 + l15; if (ar >= M) ar = M - 1;
    #pragma unroll
    for (int kt = 0; kt < 4; ++kt)
      af[rt][kt] = *(const short8*)(Ab + (size_t)ar * 128 + kt * 32 + quad * 8);
  }
  const int NCc = NT * 16;
  for (int nt = 0; nt < NT; ++nt) {
    f32x4 a0 = {0.f,0.f,0.f,0.f}, a1 = {0.f,0.f,0.f,0.f};
    #pragma unroll
    for (int kt = 0; kt < 4; ++kt) {
      short8 b = *(const short8*)(Bp + (((size_t)(nt * 4 + kt) * 64) + lane) * 8);
      a0 = __builtin_amdgcn_mfma_f32_16x16x32_bf16(af[0][kt], b, a0, 0, 0, 0);
      a1 = __builtin_amdgcn_mfma_f32_16x16x32_bf16(af[1][kt], b, a1, 0, 0, 0);
    }
    int c = nt * 16 + l15;
    float bv = bias ? bias[c] : 0.f;
    #pragma unroll
    for (int rt = 0; rt < 2; ++rt) {
      f32x4 acc = rt ? a1 : a0;
      #pragma unroll
      for (int reg = 0; reg < 4; ++reg) {
        int r = row0 + rt * 16 + quad * 4 + reg;
        if (r < M) {
          float v = acc[reg] + bv;
          if (OUT_BF16) ((short*)Cout)[(size_t)r * NCc + c] = f2bf(v);
          else ((float*)Cout)[(size_t)r * NCc + c] = v;
        }
      }
    }
  }
}

// ---------- message aggregate (bf16 t): a[n] = sum_{e: dst=n} t[src*4+etype] ----------
__global__ __launch_bounds__(256) void k_aggregate(const short* __restrict__ t,
    const int* __restrict__ row_ofs, const int* __restrict__ csr_row,
    short* __restrict__ ab, int N) {
  int node = blockIdx.x * 4 + (threadIdx.x >> 6);
  int lane = threadIdx.x & 63;
  if (node >= N) return;
  int beg = row_ofs[node], end = row_ofs[node + 1];
  float ax = 0.f, ay = 0.f;
  for (int base = beg; base < end; base += 64) {
    int nv = end - base; if (nv > 64) nv = 64;
    int r = (lane < nv) ? csr_row[base + lane] : 0;
    #pragma unroll 2
    for (int j = 0; j < nv; ++j) {
      int rr = __shfl(r, j);
      unsigned v = ((const unsigned*)(t + (size_t)rr * 128))[lane];
      ax += bflo(v);
      ay += bfhi(v);
    }
  }
  unsigned o = ((unsigned)(unsigned short)f2bf(ay) << 16) | (unsigned short)f2bf(ax);
  ((unsigned*)(ab + (size_t)node * 128))[lane] = o;
}

// ---------- fused GRU via MFMA, 32 rows/wave ----------
__global__ __launch_bounds__(256) void k_gru_mfma(const short* __restrict__ ab,
    short* __restrict__ hb, float* __restrict__ hf,
    const short* __restrict__ Pih, const short* __restrict__ Phh,
    const float* __restrict__ b_ih, const float* __restrict__ b_hh, int M) {
  int tid = threadIdx.x;
  int lane = tid & 63, wave = tid >> 6;
  int row0 = blockIdx.x * 128 + wave * 32;
  int quad = lane >> 4, l15 = lane & 15;
  short8 fa[2][4], fh[2][4];
  #pragma unroll
  for (int rt = 0; rt < 2; ++rt) {
    int ar = row0 + rt * 16 + l15; if (ar >= M) ar = M - 1;
    #pragma unroll
    for (int kt = 0; kt < 4; ++kt) {
      fa[rt][kt] = *(const short8*)(ab + (size_t)ar * 128 + kt * 32 + quad * 8);
      fh[rt][kt] = *(const short8*)(hb + (size_t)ar * 128 + kt * 32 + quad * 8);
    }
  }
  for (int nt = 0; nt < 8; ++nt) {
    f32x4 accr[2], accz[2], acci[2], acch[2];
    #pragma unroll
    for (int rt = 0; rt < 2; ++rt) {
      accr[rt] = {0.f,0.f,0.f,0.f}; accz[rt] = {0.f,0.f,0.f,0.f};
      acci[rt] = {0.f,0.f,0.f,0.f}; acch[rt] = {0.f,0.f,0.f,0.f};
    }
    #pragma unroll
    for (int kt = 0; kt < 4; ++kt) {
      size_t li = ((size_t)lane) * 8;
      short8 wr = *(const short8*)(Pih + ((size_t)((nt     ) * 4 + kt) * 64) * 8 + li);
      short8 wz = *(const short8*)(Pih + ((size_t)((nt +  8) * 4 + kt) * 64) * 8 + li);
      short8 wn = *(const short8*)(Pih + ((size_t)((nt + 16) * 4 + kt) * 64) * 8 + li);
      short8 ur = *(const short8*)(Phh + ((size_t)((nt     ) * 4 + kt) * 64) * 8 + li);
      short8 uz = *(const short8*)(Phh + ((size_t)((nt +  8) * 4 + kt) * 64) * 8 + li);
      short8 un = *(const short8*)(Phh + ((size_t)((nt + 16) * 4 + kt) * 64) * 8 + li);
      #pragma unroll
      for (int rt = 0; rt < 2; ++rt) {
        accr[rt] = __builtin_amdgcn_mfma_f32_16x16x32_bf16(fa[rt][kt], wr, accr[rt], 0, 0, 0);
        accr[rt] = __builtin_amdgcn_mfma_f32_16x16x32_bf16(fh[rt][kt], ur, accr[rt], 0, 0, 0);
        accz[rt] = __builtin_amdgcn_mfma_f32_16x16x32_bf16(fa[rt][kt], wz, accz[rt], 0, 0, 0);
        accz[rt] = __builtin_amdgcn_mfma_f32_16x16x32_bf16(fh[rt][kt], uz, accz[rt], 0, 0, 0);
        acci[rt] = __builtin_amdgcn_mfma_f32_16x16x32_bf16(fa[rt][kt], wn, acci[rt], 0, 0, 0);
        acch[rt] = __builtin_amdgcn_mfma_f32_16x16x32_bf16(fh[rt][kt], un, acch[rt], 0, 0, 0);
      }
    }
    int c = nt * 16 + l15;
    float bir = b_ih[c],      bhr = b_hh[c];
    float biz = b_ih[c+128],  bhz = b_hh[c+128];
    float bin_= b_ih[c+256],  bhn = b_hh[c+256];
    #pragma unroll
    for (int rt = 0; rt < 2; ++rt) {
      #pragma unroll
      for (int reg = 0; reg < 4; ++reg) {
        int r = row0 + rt * 16 + quad * 4 + reg;
        if (r < M) {
          float rg = sigf(accr[rt][reg] + bir + bhr);
          float zg = sigf(accz[rt][reg] + biz + bhz);
          float ng = tanhf(acci[rt][reg] + bin_ + rg * (acch[rt][reg] + bhn));
          float hold = hf[(size_t)r * 128 + c];
          float hn2 = (1.f - zg) * ng + zg * hold;
          hf[(size_t)r * 128 + c] = hn2;
          hb[(size_t)r * 128 + c] = f2bf(hn2);
        }
      }
    }
  }
}

// ---------- L2 normalize + sigmoid: hf (fp32) -> hb (bf16) ----------
__global__ __launch_bounds__(256) void k_norm_sig(const float* __restrict__ hf,
    short* __restrict__ hb, int N) {
  int node = blockIdx.x * 4 + (threadIdx.x >> 6);
  int lane = threadIdx.x & 63;
  if (node >= N) return;
  float2 v = ((const float2*)(hf + (size_t)node * D))[lane];
  float s = v.x * v.x + v.y * v.y;
  #pragma unroll
  for (int off = 32; off; off >>= 1) s += __shfl_xor(s, off);
  float inv = 1.f / fmaxf(sqrtf(s), 1e-12f);
  float x = sigf(v.x * inv), y = sigf(v.y * inv);
  unsigned o = ((unsigned)(unsigned short)f2bf(y) << 16) | (unsigned short)f2bf(x);
  ((unsigned*)(hb + (size_t)node * D))[lane] = o;
}

// ---------- el/er per node per head (bf16 zft) ----------
__global__ __launch_bounds__(256) void k_eler(const short* __restrict__ zb,
    const float* __restrict__ attn_l, const float* __restrict__ attn_r,
    float* __restrict__ el, float* __restrict__ er, int N) {
  int node = blockIdx.x * 4 + (threadIdx.x >> 6);
  int lane = threadIdx.x & 63;
  if (node >= N) return;
  uint2 zv = ((const uint2*)(zb + (size_t)node * 256))[lane];
  float z0 = bflo(zv.x), z1 = bfhi(zv.x), z2 = bflo(zv.y), z3 = bfhi(zv.y);
  float4 al = ((const float4*)attn_l)[lane];
  float4 ar = ((const float4*)attn_r)[lane];
  float pl = z0 * al.x + z1 * al.y + z2 * al.z + z3 * al.w;
  float pr = z0 * ar.x + z1 * ar.y + z2 * ar.z + z3 * ar.w;
  #pragma unroll
  for (int off = 16; off; off >>= 1) { pl += __shfl_xor(pl, off); pr += __shfl_xor(pr, off); }
  if ((lane & 31) == 0) {
    int hh = lane >> 5;
    el[node * 2 + hh] = pl;
    er[node * 2 + hh] = pr;
  }
}

// ---------- GAT aggregation (online softmax per dst node, bf16 zft gather) ----------
__global__ __launch_bounds__(256) void k_gat(const short* __restrict__ zb,
    const float* __restrict__ el, const float* __restrict__ er,
    const int* __restrict__ row_ofs, const int* __restrict__ csr_src,
    const float* __restrict__ gat_bias, float* __restrict__ out, int N) {
  int node = blockIdx.x * 4 + (threadIdx.x >> 6);
  int lane = threadIdx.x & 63;
  if (node >= N) return;
  int beg = row_ofs[node], end = row_ofs[node + 1];
  float2 ern = ((const float2*)er)[node];
  float m0 = -INFINITY, m1 = -INFINITY, l0 = 0.f, l1 = 0.f;
  float4 acc = {0.f, 0.f, 0.f, 0.f};
  int head = lane >> 5;
  for (int base = beg; base < end; base += 64) {
    int nv = end - base; if (nv > 64) nv = 64;
    int sidx = (lane < nv) ? csr_src[base + lane] : 0;
    float e0 = -INFINITY, e1 = -INFINITY;
    if (lane < nv) {
      float2 els = ((const float2*)el)[sidx];
      e0 = lrelu(els.x + ern.x);
      e1 = lrelu(els.y + ern.y);
    }
    float c0 = e0, c1 = e1;
    #pragma unroll
    for (int off = 32; off; off >>= 1) {
      c0 = fmaxf(c0, __shfl_xor(c0, off));
      c1 = fmaxf(c1, __shfl_xor(c1, off));
    }
    float nm0 = fmaxf(m0, c0), nm1 = fmaxf(m1, c1);
    float s0 = expf(m0 - nm0), s1 = expf(m1 - nm1);
    float p0 = (lane < nv) ? expf(e0 - nm0) : 0.f;
    float p1 = (lane < nv) ? expf(e1 - nm1) : 0.f;
    float t0 = p0, t1 = p1;
    #pragma unroll
    for (int off = 32; off; off >>= 1) { t0 += __shfl_xor(t0, off); t1 += __shfl_xor(t1, off); }
    float sc = head ? s1 : s0;
    acc.x *= sc; acc.y *= sc; acc.z *= sc; acc.w *= sc;
    l0 = l0 * s0 + t0; l1 = l1 * s1 + t1;
    m0 = nm0; m1 = nm1;
    #pragma unroll 2
    for (int j = 0; j < nv; ++j) {
      int sj = __shfl(sidx, j);
      float pj0 = __shfl(p0, j), pj1 = __shfl(p1, j);
      float w = head ? pj1 : pj0;
      uint2 zv = ((const uint2*)(zb + (size_t)sj * 256))[lane];
      acc.x += w * bflo(zv.x); acc.y += w * bfhi(zv.x);
      acc.z += w * bflo(zv.y); acc.w += w * bfhi(zv.y);
    }
  }
  float inv0 = (l0 > 0.f) ? 1.f / l0 : 0.f;
  float inv1 = (l1 > 0.f) ? 1.f / l1 : 0.f;
  float inv = head ? inv1 : inv0;
  float4 b = ((const float4*)gat_bias)[lane];
  float4 o;
  o.x = fmaxf(acc.x * inv + b.x, 0.f);
  o.y = fmaxf(acc.y * inv + b.y, 0.f);
  o.z = fmaxf(acc.z * inv + b.z, 0.f);
  o.w = fmaxf(acc.w * inv + b.w, 0.f);
  ((float4*)(out + (size_t)node * 256))[lane] = o;
}

// ---------- parallel segmented per-graph sums ----------
__global__ __launch_bounds__(256) void k_segred(const float* __restrict__ hgat,
    const int* __restrict__ gidc, float* __restrict__ sums, int NT2) {
  int node0 = blockIdx.x * 128;
  int col = threadIdx.x;
  int end = node0 + 128; if (end > NT2) end = NT2;
  if (node0 >= NT2) return;
  float acc = 0.f;
  int gcur = gidc[node0];
  for (int n = node0; n < end; ++n) {
    int g = gidc[n];
    if (g != gcur) {
      atomicAdd(&sums[gcur * 256 + col], acc);
      acc = 0.f; gcur = g;
    }
    acc += hgat[(size_t)n * 256 + col];
  }
  atomicAdd(&sums[gcur * 256 + col], acc);
}

// ---------- mean + classifier ----------
__global__ __launch_bounds__(64) void k_classify(const float* __restrict__ sums,
    const int* __restrict__ gcnt, const float* __restrict__ W_cls,
    const float* __restrict__ b_cls, float* __restrict__ logits) {
  int g = blockIdx.x, tid = threadIdx.x;
  int hh = tid >> 5, c = tid & 31;
  float invc = 1.f / fmaxf((float)gcnt[g], 1.f);
  float acc = 0.f;
  for (int d = 0; d < D; ++d)
    acc += (sums[g * 256 + hh * D + d] * invc) * W_cls[c * D + d];
  logits[g * 64 + hh * 32 + c] = acc + b_cls[c];
}

// ---------- pairwise distance + softmax over heads (graph g vs g+64) ----------
__global__ __launch_bounds__(64) void k_final(const float* __restrict__ logits,
    float* __restrict__ out) {
  int g = threadIdx.x;
  if (g >= NG) return;
  float d[2];
  #pragma unroll
  for (int hh = 0; hh < 2; ++hh) {
    float s = 0.f;
    for (int c = 0; c < 32; ++c) {
      float df = logits[g * 64 + hh * 32 + c] - logits[(g + NG) * 64 + hh * 32 + c] + 1e-6f;
      s += df * df;
    }
    d[hh] = sqrtf(s);
  }
  float mx = fmaxf(d[0], d[1]);
  float e0 = expf(d[0] - mx), e1 = expf(d[1] - mx);
  float den = e0 + e1;
  out[g * 2] = e0 / den;
  out[g * 2 + 1] = e1 / den;
}

extern "C" void kernel_launch(void* const* d_in, const int* in_sizes, int n_in,
                              void* d_out, int out_size, void* d_ws, size_t ws_size,
                              hipStream_t stream) {
  const float* in_feat1 = (const float*)d_in[0];
  const float* in_feat2 = (const float*)d_in[1];
  const int* src1 = (const int*)d_in[2];
  const int* dst1 = (const int*)d_in[3];
  const int* ety1 = (const int*)d_in[4];
  const int* gid1 = (const int*)d_in[5];
  const int* src2 = (const int*)d_in[6];
  const int* dst2 = (const int*)d_in[7];
  const int* ety2 = (const int*)d_in[8];
  const int* gid2 = (const int*)d_in[9];
  const float* W_et = (const float*)d_in[10];
  const float* b_et = (const float*)d_in[11];
  const float* W_ih = (const float*)d_in[12];
  const float* W_hh = (const float*)d_in[13];
  const float* b_ih = (const float*)d_in[14];
  const float* b_hh = (const float*)d_in[15];
  const float* W_fc = (const float*)d_in[16];
  const float* attn_l = (const float*)d_in[17];
  const float* attn_r = (const float*)d_in[18];
  const float* gat_bias = (const float*)d_in[19];
  const float* W_cls = (const float*)d_in[20];
  const float* b_cls = (const float*)d_in[21];
  float* out = (float*)d_out;

  int N = in_sizes[0] / D;
  int E = in_sizes[2];
  int N2 = 2 * N, E2 = 2 * E;

  char* p = (char*)d_ws;
  auto alloc = [&](size_t bytes) -> void* {
    char* r = p;
    p += (bytes + 255) & ~(size_t)255;
    return (void*)r;
  };
  short* WetP = (short*)alloc((size_t)512 * 128 * 2);
  short* WihP = (short*)alloc((size_t)384 * 128 * 2);
  short* WhhP = (short*)alloc((size_t)384 * 128 * 2);
  short* WfcP = (short*)alloc((size_t)256 * 128 * 2);
  float* hf  = (float*)alloc((size_t)N2 * D * 4);     // fp32 h state; reused as zb after norm
  short* hb  = (short*)alloc((size_t)N2 * D * 2);
  short* ab  = (short*)alloc((size_t)N2 * D * 2);
  short* t   = (short*)alloc((size_t)N2 * 512 * 2);   // bf16 messages; reused as hgat
  float* el  = (float*)alloc((size_t)N2 * 2 * 4);
  float* er  = (float*)alloc((size_t)N2 * 2 * 4);
  float* sums= (float*)alloc((size_t)NG2 * 256 * 4);
  float* logits = (float*)alloc((size_t)NG2 * 64 * 4);
  int* deg     = (int*)alloc((size_t)N2 * 4);
  int* row_ofs = (int*)alloc(((size_t)N2 + 1) * 4);
  int* cursor  = (int*)alloc((size_t)N2 * 4);
  int* gidc    = (int*)alloc((size_t)N2 * 4);
  int* gcnt    = (int*)alloc((size_t)NG2 * 4);
  int* csr_src = (int*)alloc((size_t)E2 * 4);
  int* csr_row = (int*)alloc((size_t)E2 * 4);
  if ((size_t)(p - (char*)d_ws) > ws_size) return;

  short* zb = (short*)hf;     // [N2,256] bf16 — overlays hf (dead after norm_sig)
  float* hgat = (float*)t;    // [N2,256] fp32 — overlays t (dead after last aggregate)

  // weight packing
  k_pack<<<dim3(64), dim3(256), 0, stream>>>(W_et, WetP, 512);
  k_pack<<<dim3(48), dim3(256), 0, stream>>>(W_ih, WihP, 384);
  k_pack<<<dim3(48), dim3(256), 0, stream>>>(W_hh, WhhP, 384);
  k_pack<<<dim3(32), dim3(256), 0, stream>>>(W_fc, WfcP, 256);

  // CSR for merged graph
  hipMemsetAsync(deg, 0, (size_t)N2 * 4, stream);
  hipMemsetAsync(gcnt, 0, (size_t)NG2 * 4, stream);
  int eb = (E2 + 255) / 256;
  k_hist<<<dim3(eb), dim3(256), 0, stream>>>(dst1, dst2, E, N, deg);
  k_scan<<<dim3(1), dim3(1024), 0, stream>>>(deg, row_ofs, cursor, N2);
  k_scatter<<<dim3(eb), dim3(256), 0, stream>>>(src1, dst1, ety1, src2, dst2, ety2,
                                                E, N, cursor, csr_src, csr_row);
  k_fillgid<<<dim3((N2 + 255) / 256), dim3(256), 0, stream>>>(gid1, gid2, N, gidc, gcnt);

  // init h
  hipMemcpyAsync(hf, in_feat1, (size_t)N * D * 4, hipMemcpyDeviceToDevice, stream);
  hipMemcpyAsync(hf + (size_t)N * D, in_feat2, (size_t)N * D * 4,
                 hipMemcpyDeviceToDevice, stream);
  k_cvt<<<dim3(1024), dim3(256), 0, stream>>>(hf, hb, N2 * D / 4);

  int gb = (N2 + 127) / 128;
  int nb4 = (N2 + 3) / 4;

  for (int s = 0; s < NSTEPS; ++s) {
    k_mfma_gemm<32, true><<<dim3(gb), dim3(256), 0, stream>>>(hb, WetP, b_et, t, N2);
    k_aggregate<<<dim3(nb4), dim3(256), 0, stream>>>(t, row_ofs, csr_row, ab, N2);
    k_gru_mfma<<<dim3(gb), dim3(256), 0, stream>>>(ab, hb, hf, WihP, WhhP, b_ih, b_hh, N2);
  }
  k_norm_sig<<<dim3(nb4), dim3(256), 0, stream>>>(hf, hb, N2);
  k_mfma_gemm<16, true><<<dim3(gb), dim3(256), 0, stream>>>(hb, WfcP, nullptr, zb, N2);
  k_eler<<<dim3(nb4), dim3(256), 0, stream>>>(zb, attn_l, attn_r, el, er, N2);
  k_gat<<<dim3(nb4), dim3(256), 0, stream>>>(zb, el, er, row_ofs, csr_src,
                                             gat_bias, hgat, N2);
  hipMemsetAsync(sums, 0, (size_t)NG2 * 256 * 4, stream);
  k_segred<<<dim3((N2 + 127) / 128), dim3(256), 0, stream>>>(hgat, gidc, sums, N2);
  k_classify<<<dim3(NG2), dim3(64), 0, stream>>>(sums, gcnt, W_cls, b_cls, logits);
  k_final<<<dim3(1), dim3(64), 0, stream>>>(logits, out);
}

// Round 4
// 1585.849 us; speedup vs baseline: 3.0331x; 1.2201x over previous
//
#include <hip/hip_runtime.h>
#include <math.h>

#define D 128
#define NG 64
#define NG2 128
#define NSTEPS 5

using short8 = __attribute__((ext_vector_type(8))) short;
using f32x4  = __attribute__((ext_vector_type(4))) float;

__device__ __forceinline__ float sigf(float x) { return 1.f / (1.f + expf(-x)); }
__device__ __forceinline__ float lrelu(float x) { return x > 0.f ? x : 0.2f * x; }
__device__ __forceinline__ short f2bf(float x) {
  unsigned u = __float_as_uint(x);
  u += 0x7fff + ((u >> 16) & 1);
  return (short)(u >> 16);
}
__device__ __forceinline__ float bflo(unsigned v) { return __uint_as_float(v << 16); }
__device__ __forceinline__ float bfhi(unsigned v) { return __uint_as_float(v & 0xffff0000u); }
__device__ __forceinline__ float bf2f(short s) {
  return __uint_as_float(((unsigned)(unsigned short)s) << 16);
}

// ---------- init: concat(in_feat1,in_feat2) -> hb (bf16) ----------
__global__ void k_init(const float* __restrict__ f1, const float* __restrict__ f2,
                       short* __restrict__ hb, int Nd4) {
  int tot = 2 * Nd4;
  for (int i = blockIdx.x * blockDim.x + threadIdx.x; i < tot; i += gridDim.x * blockDim.x) {
    float4 v = (i < Nd4) ? ((const float4*)f1)[i] : ((const float4*)f2)[i - Nd4];
    unsigned lo = ((unsigned)(unsigned short)f2bf(v.y) << 16) | (unsigned short)f2bf(v.x);
    unsigned hi = ((unsigned)(unsigned short)f2bf(v.w) << 16) | (unsigned short)f2bf(v.z);
    ((uint2*)hb)[i] = make_uint2(lo, hi);
  }
}

// ---------- pack W[NC][128] into MFMA b-frag order ----------
__global__ void k_pack(const float* __restrict__ W, short* __restrict__ P, int NC) {
  int n = NC * 128;
  for (int i = blockIdx.x * blockDim.x + threadIdx.x; i < n; i += gridDim.x * blockDim.x) {
    int j = i & 7;
    int lane = (i >> 3) & 63;
    int kt = (i >> 9) & 3;
    int nt = i >> 11;
    int c = nt * 16 + (lane & 15);
    int k = kt * 32 + ((lane >> 4) << 3) + j;
    P[i] = f2bf(W[c * 128 + k]);
  }
}

// ---------- CSR build over merged graph ----------
__global__ void k_hist(const int* __restrict__ dst1, const int* __restrict__ dst2,
                       int E, int N, int* __restrict__ deg) {
  for (int e = blockIdx.x * blockDim.x + threadIdx.x; e < 2 * E; e += gridDim.x * blockDim.x) {
    int d = (e < E) ? dst1[e] : dst2[e - E] + N;
    atomicAdd(&deg[d], 1);
  }
}

// hierarchical exclusive scan: a) block sums, b) scan of block sums, c) write
__global__ __launch_bounds__(256) void k_scan_a(const int* __restrict__ deg, int n,
                                                int* __restrict__ bsum) {
  int base = blockIdx.x * 1024 + threadIdx.x * 4;
  int s = 0;
  if (base + 3 < n) {
    int4 v = *(const int4*)(deg + base);
    s = v.x + v.y + v.z + v.w;
  } else {
    for (int k = 0; k < 4; ++k) if (base + k < n) s += deg[base + k];
  }
  #pragma unroll
  for (int off = 32; off; off >>= 1) s += __shfl_xor(s, off);
  __shared__ int ws[4];
  if ((threadIdx.x & 63) == 0) ws[threadIdx.x >> 6] = s;
  __syncthreads();
  if (threadIdx.x == 0) bsum[blockIdx.x] = ws[0] + ws[1] + ws[2] + ws[3];
}

__global__ __launch_bounds__(1024) void k_scan_b(const int* __restrict__ bsum,
                                                 int* __restrict__ boffs, int nb) {
  int tid = threadIdx.x;
  int v = (tid < nb) ? bsum[tid] : 0;
  int lane = tid & 63, wv = tid >> 6;
  int x = v;
  #pragma unroll
  for (int off = 1; off < 64; off <<= 1) {
    int y = __shfl_up(x, off);
    if (lane >= off) x += y;
  }
  __shared__ int wsum[16];
  if (lane == 63) wsum[wv] = x;
  __syncthreads();
  if (tid < 16) {
    int u = wsum[tid];
    #pragma unroll
    for (int off = 1; off < 16; off <<= 1) {
      int y = __shfl_up(u, off);
      if (tid >= off) u += y;
    }
    wsum[tid] = u;
  }
  __syncthreads();
  int woff = wv ? wsum[wv - 1] : 0;
  if (tid < nb) boffs[tid] = woff + x - v;
}

__global__ __launch_bounds__(256) void k_scan_c(const int* __restrict__ deg,
    const int* __restrict__ boffs, int* __restrict__ row_ofs,
    int* __restrict__ cursor, int n) {
  int base = blockIdx.x * 1024 + threadIdx.x * 4;
  int v[4] = {0, 0, 0, 0};
  if (base + 3 < n) {
    int4 t = *(const int4*)(deg + base);
    v[0] = t.x; v[1] = t.y; v[2] = t.z; v[3] = t.w;
  } else {
    for (int k = 0; k < 4; ++k) if (base + k < n) v[k] = deg[base + k];
  }
  int s = v[0] + v[1] + v[2] + v[3];
  int lane = threadIdx.x & 63, wv = threadIdx.x >> 6;
  int x = s;
  #pragma unroll
  for (int off = 1; off < 64; off <<= 1) {
    int y = __shfl_up(x, off);
    if (lane >= off) x += y;
  }
  __shared__ int wsum[4];
  if (lane == 63) wsum[wv] = x;
  __syncthreads();
  int woff = 0;
  for (int w = 0; w < wv; ++w) woff += wsum[w];
  int run = boffs[blockIdx.x] + woff + x - s;
  #pragma unroll
  for (int k = 0; k < 4; ++k) {
    int i = base + k;
    if (i < n) {
      cursor[i] = run;
      run += v[k];
      row_ofs[i + 1] = run;
    }
  }
  if (blockIdx.x == 0 && threadIdx.x == 0) row_ofs[0] = 0;
}

__global__ void k_scatter(const int* __restrict__ src1, const int* __restrict__ dst1,
                          const int* __restrict__ ety1, const int* __restrict__ src2,
                          const int* __restrict__ dst2, const int* __restrict__ ety2,
                          int E, int N, int* __restrict__ cursor,
                          int* __restrict__ csr_src, int* __restrict__ csr_row) {
  for (int e = blockIdx.x * blockDim.x + threadIdx.x; e < 2 * E; e += gridDim.x * blockDim.x) {
    int s, d, et;
    if (e < E) { s = src1[e]; d = dst1[e]; et = ety1[e]; }
    else { s = src2[e - E] + N; d = dst2[e - E] + N; et = ety2[e - E]; }
    int p = atomicAdd(&cursor[d], 1);
    csr_src[p] = s;
    csr_row[p] = s * 4 + et;
  }
}

// ---------- merged gid array [2N] + per-graph counts [128] ----------
__global__ void k_fillgid(const int* __restrict__ gid1, const int* __restrict__ gid2,
                          int N, int* __restrict__ gidc, int* __restrict__ gcnt) {
  __shared__ int cnt[NG2];
  int t = threadIdx.x;
  if (t < NG2) cnt[t] = 0;
  __syncthreads();
  int i = blockIdx.x * 256 + t;
  if (i < 2 * N) {
    int g = (i < N) ? gid1[i] : gid2[i - N] + NG;
    gidc[i] = g;
    atomicAdd(&cnt[g], 1);
  }
  __syncthreads();
  if (t < NG2 && cnt[t]) atomicAdd(&gcnt[t], cnt[t]);
}

// ---------- MFMA GEMM, 32 rows/wave: C[M, NT*16] = A_bf16[M,128] @ Bp (+bias) ----------
template <int NT, bool OUT_BF16>
__global__ __launch_bounds__(256) void k_mfma_gemm(const short* __restrict__ Ab,
    const short* __restrict__ Bp, const float* __restrict__ bias,
    void* __restrict__ Cout, int M) {
  int tid = threadIdx.x;
  int lane = tid & 63, wave = tid >> 6;
  int row0 = blockIdx.x * 128 + wave * 32;
  int quad = lane >> 4, l15 = lane & 15;
  short8 af[2][4];
  #pragma unroll
  for (int rt = 0; rt < 2; ++rt) {
    int ar = row0 + rt * 16 + l15; if (ar >= M) ar = M - 1;
    #pragma unroll
    for (int kt = 0; kt < 4; ++kt)
      af[rt][kt] = *(const short8*)(Ab + (size_t)ar * 128 + kt * 32 + quad * 8);
  }
  const int NCc = NT * 16;
  for (int nt = 0; nt < NT; ++nt) {
    f32x4 a0 = {0.f,0.f,0.f,0.f}, a1 = {0.f,0.f,0.f,0.f};
    #pragma unroll
    for (int kt = 0; kt < 4; ++kt) {
      short8 b = *(const short8*)(Bp + (((size_t)(nt * 4 + kt) * 64) + lane) * 8);
      a0 = __builtin_amdgcn_mfma_f32_16x16x32_bf16(af[0][kt], b, a0, 0, 0, 0);
      a1 = __builtin_amdgcn_mfma_f32_16x16x32_bf16(af[1][kt], b, a1, 0, 0, 0);
    }
    int c = nt * 16 + l15;
    float bv = bias ? bias[c] : 0.f;
    #pragma unroll
    for (int rt = 0; rt < 2; ++rt) {
      f32x4 acc = rt ? a1 : a0;
      #pragma unroll
      for (int reg = 0; reg < 4; ++reg) {
        int r = row0 + rt * 16 + quad * 4 + reg;
        if (r < M) {
          float v = acc[reg] + bv;
          if (OUT_BF16) ((short*)Cout)[(size_t)r * NCc + c] = f2bf(v);
          else ((float*)Cout)[(size_t)r * NCc + c] = v;
        }
      }
    }
  }
}

// ---------- fc GEMM (NT=16) fused with el/er reduction ----------
__global__ __launch_bounds__(256) void k_fc_eler(const short* __restrict__ Ab,
    const short* __restrict__ Bp, const float* __restrict__ attn_l,
    const float* __restrict__ attn_r, short* __restrict__ zb,
    float* __restrict__ el, float* __restrict__ er, int M) {
  int tid = threadIdx.x;
  int lane = tid & 63, wave = tid >> 6;
  int row0 = blockIdx.x * 128 + wave * 32;
  int quad = lane >> 4, l15 = lane & 15;
  short8 af[2][4];
  #pragma unroll
  for (int rt = 0; rt < 2; ++rt) {
    int ar = row0 + rt * 16 + l15; if (ar >= M) ar = M - 1;
    #pragma unroll
    for (int kt = 0; kt < 4; ++kt)
      af[rt][kt] = *(const short8*)(Ab + (size_t)ar * 128 + kt * 32 + quad * 8);
  }
  float elp[2][2][4] = {};
  float erp[2][2][4] = {};
  for (int nt = 0; nt < 16; ++nt) {
    f32x4 a0 = {0.f,0.f,0.f,0.f}, a1 = {0.f,0.f,0.f,0.f};
    #pragma unroll
    for (int kt = 0; kt < 4; ++kt) {
      short8 b = *(const short8*)(Bp + (((size_t)(nt * 4 + kt) * 64) + lane) * 8);
      a0 = __builtin_amdgcn_mfma_f32_16x16x32_bf16(af[0][kt], b, a0, 0, 0, 0);
      a1 = __builtin_amdgcn_mfma_f32_16x16x32_bf16(af[1][kt], b, a1, 0, 0, 0);
    }
    int head = nt >> 3;
    int colh = (nt & 7) * 16 + l15;
    float alv = attn_l[head * 128 + colh];
    float arv = attn_r[head * 128 + colh];
    int c = nt * 16 + l15;
    #pragma unroll
    for (int rt = 0; rt < 2; ++rt) {
      f32x4 acc = rt ? a1 : a0;
      #pragma unroll
      for (int reg = 0; reg < 4; ++reg) {
        int r = row0 + rt * 16 + quad * 4 + reg;
        if (r < M) zb[(size_t)r * 256 + c] = f2bf(acc[reg]);
        elp[rt][head][reg] += acc[reg] * alv;
        erp[rt][head][reg] += acc[reg] * arv;
      }
    }
  }
  // reduce partials across l15 lanes (within each quad)
  #pragma unroll
  for (int off = 1; off < 16; off <<= 1) {
    #pragma unroll
    for (int rt = 0; rt < 2; ++rt)
      #pragma unroll
      for (int h = 0; h < 2; ++h)
        #pragma unroll
        for (int reg = 0; reg < 4; ++reg) {
          elp[rt][h][reg] += __shfl_xor(elp[rt][h][reg], off);
          erp[rt][h][reg] += __shfl_xor(erp[rt][h][reg], off);
        }
  }
  if (l15 == 0) {
    #pragma unroll
    for (int rt = 0; rt < 2; ++rt)
      #pragma unroll
      for (int h = 0; h < 2; ++h)
        #pragma unroll
        for (int reg = 0; reg < 4; ++reg) {
          int r = row0 + rt * 16 + quad * 4 + reg;
          if (r < M) {
            el[r * 2 + h] = elp[rt][h][reg];
            er[r * 2 + h] = erp[rt][h][reg];
          }
        }
  }
}

// ---------- message aggregate (bf16 t): a[n] = sum_{e: dst=n} t[src*4+etype] ----------
__global__ __launch_bounds__(256) void k_aggregate(const short* __restrict__ t,
    const int* __restrict__ row_ofs, const int* __restrict__ csr_row,
    short* __restrict__ ab, int N) {
  int node = blockIdx.x * 4 + (threadIdx.x >> 6);
  int lane = threadIdx.x & 63;
  if (node >= N) return;
  int beg = row_ofs[node], end = row_ofs[node + 1];
  float ax = 0.f, ay = 0.f;
  for (int base = beg; base < end; base += 64) {
    int nv = end - base; if (nv > 64) nv = 64;
    int r = (lane < nv) ? csr_row[base + lane] : 0;
    #pragma unroll 2
    for (int j = 0; j < nv; ++j) {
      int rr = __shfl(r, j);
      unsigned v = ((const unsigned*)(t + (size_t)rr * 128))[lane];
      ax += bflo(v);
      ay += bfhi(v);
    }
  }
  unsigned o = ((unsigned)(unsigned short)f2bf(ay) << 16) | (unsigned short)f2bf(ax);
  ((unsigned*)(ab + (size_t)node * 128))[lane] = o;
}

// ---------- fused GRU via MFMA, 32 rows/wave, bf16 recurrent state ----------
__global__ __launch_bounds__(256) void k_gru_mfma(const short* __restrict__ ab,
    short* __restrict__ hb,
    const short* __restrict__ Pih, const short* __restrict__ Phh,
    const float* __restrict__ b_ih, const float* __restrict__ b_hh, int M) {
  int tid = threadIdx.x;
  int lane = tid & 63, wave = tid >> 6;
  int row0 = blockIdx.x * 128 + wave * 32;
  int quad = lane >> 4, l15 = lane & 15;
  short8 fa[2][4], fh[2][4];
  #pragma unroll
  for (int rt = 0; rt < 2; ++rt) {
    int ar = row0 + rt * 16 + l15; if (ar >= M) ar = M - 1;
    #pragma unroll
    for (int kt = 0; kt < 4; ++kt) {
      fa[rt][kt] = *(const short8*)(ab + (size_t)ar * 128 + kt * 32 + quad * 8);
      fh[rt][kt] = *(const short8*)(hb + (size_t)ar * 128 + kt * 32 + quad * 8);
    }
  }
  for (int nt = 0; nt < 8; ++nt) {
    f32x4 accr[2], accz[2], acci[2], acch[2];
    #pragma unroll
    for (int rt = 0; rt < 2; ++rt) {
      accr[rt] = {0.f,0.f,0.f,0.f}; accz[rt] = {0.f,0.f,0.f,0.f};
      acci[rt] = {0.f,0.f,0.f,0.f}; acch[rt] = {0.f,0.f,0.f,0.f};
    }
    #pragma unroll
    for (int kt = 0; kt < 4; ++kt) {
      size_t li = ((size_t)lane) * 8;
      short8 wr = *(const short8*)(Pih + ((size_t)((nt     ) * 4 + kt) * 64) * 8 + li);
      short8 wz = *(const short8*)(Pih + ((size_t)((nt +  8) * 4 + kt) * 64) * 8 + li);
      short8 wn = *(const short8*)(Pih + ((size_t)((nt + 16) * 4 + kt) * 64) * 8 + li);
      short8 ur = *(const short8*)(Phh + ((size_t)((nt     ) * 4 + kt) * 64) * 8 + li);
      short8 uz = *(const short8*)(Phh + ((size_t)((nt +  8) * 4 + kt) * 64) * 8 + li);
      short8 un = *(const short8*)(Phh + ((size_t)((nt + 16) * 4 + kt) * 64) * 8 + li);
      #pragma unroll
      for (int rt = 0; rt < 2; ++rt) {
        accr[rt] = __builtin_amdgcn_mfma_f32_16x16x32_bf16(fa[rt][kt], wr, accr[rt], 0, 0, 0);
        accr[rt] = __builtin_amdgcn_mfma_f32_16x16x32_bf16(fh[rt][kt], ur, accr[rt], 0, 0, 0);
        accz[rt] = __builtin_amdgcn_mfma_f32_16x16x32_bf16(fa[rt][kt], wz, accz[rt], 0, 0, 0);
        accz[rt] = __builtin_amdgcn_mfma_f32_16x16x32_bf16(fh[rt][kt], uz, accz[rt], 0, 0, 0);
        acci[rt] = __builtin_amdgcn_mfma_f32_16x16x32_bf16(fa[rt][kt], wn, acci[rt], 0, 0, 0);
        acch[rt] = __builtin_amdgcn_mfma_f32_16x16x32_bf16(fh[rt][kt], un, acch[rt], 0, 0, 0);
      }
    }
    int c = nt * 16 + l15;
    float bir = b_ih[c],      bhr = b_hh[c];
    float biz = b_ih[c+128],  bhz = b_hh[c+128];
    float bin_= b_ih[c+256],  bhn = b_hh[c+256];
    #pragma unroll
    for (int rt = 0; rt < 2; ++rt) {
      #pragma unroll
      for (int reg = 0; reg < 4; ++reg) {
        int r = row0 + rt * 16 + quad * 4 + reg;
        if (r < M) {
          float rg = sigf(accr[rt][reg] + bir + bhr);
          float zg = sigf(accz[rt][reg] + biz + bhz);
          float ng = tanhf(acci[rt][reg] + bin_ + rg * (acch[rt][reg] + bhn));
          float hold = bf2f(hb[(size_t)r * 128 + c]);
          float hn2 = (1.f - zg) * ng + zg * hold;
          hb[(size_t)r * 128 + c] = f2bf(hn2);
        }
      }
    }
  }
}

// ---------- L2 normalize + sigmoid on hb (bf16, in place) ----------
__global__ __launch_bounds__(256) void k_norm_sig(short* __restrict__ hb, int N) {
  int node = blockIdx.x * 4 + (threadIdx.x >> 6);
  int lane = threadIdx.x & 63;
  if (node >= N) return;
  unsigned v = ((const unsigned*)(hb + (size_t)node * D))[lane];
  float x = bflo(v), y = bfhi(v);
  float s = x * x + y * y;
  #pragma unroll
  for (int off = 32; off; off >>= 1) s += __shfl_xor(s, off);
  float inv = 1.f / fmaxf(sqrtf(s), 1e-12f);
  float xs = sigf(x * inv), ys = sigf(y * inv);
  unsigned o = ((unsigned)(unsigned short)f2bf(ys) << 16) | (unsigned short)f2bf(xs);
  ((unsigned*)(hb + (size_t)node * D))[lane] = o;
}

// ---------- GAT aggregation (online softmax per dst node, bf16 zft gather) ----------
__global__ __launch_bounds__(256) void k_gat(const short* __restrict__ zb,
    const float* __restrict__ el, const float* __restrict__ er,
    const int* __restrict__ row_ofs, const int* __restrict__ csr_src,
    const float* __restrict__ gat_bias, float* __restrict__ out, int N) {
  int node = blockIdx.x * 4 + (threadIdx.x >> 6);
  int lane = threadIdx.x & 63;
  if (node >= N) return;
  int beg = row_ofs[node], end = row_ofs[node + 1];
  float2 ern = ((const float2*)er)[node];
  float m0 = -INFINITY, m1 = -INFINITY, l0 = 0.f, l1 = 0.f;
  float4 acc = {0.f, 0.f, 0.f, 0.f};
  int head = lane >> 5;
  for (int base = beg; base < end; base += 64) {
    int nv = end - base; if (nv > 64) nv = 64;
    int sidx = (lane < nv) ? csr_src[base + lane] : 0;
    float e0 = -INFINITY, e1 = -INFINITY;
    if (lane < nv) {
      float2 els = ((const float2*)el)[sidx];
      e0 = lrelu(els.x + ern.x);
      e1 = lrelu(els.y + ern.y);
    }
    float c0 = e0, c1 = e1;
    #pragma unroll
    for (int off = 32; off; off >>= 1) {
      c0 = fmaxf(c0, __shfl_xor(c0, off));
      c1 = fmaxf(c1, __shfl_xor(c1, off));
    }
    float nm0 = fmaxf(m0, c0), nm1 = fmaxf(m1, c1);
    float s0 = expf(m0 - nm0), s1 = expf(m1 - nm1);
    float p0 = (lane < nv) ? expf(e0 - nm0) : 0.f;
    float p1 = (lane < nv) ? expf(e1 - nm1) : 0.f;
    float t0 = p0, t1 = p1;
    #pragma unroll
    for (int off = 32; off; off >>= 1) { t0 += __shfl_xor(t0, off); t1 += __shfl_xor(t1, off); }
    float sc = head ? s1 : s0;
    acc.x *= sc; acc.y *= sc; acc.z *= sc; acc.w *= sc;
    l0 = l0 * s0 + t0; l1 = l1 * s1 + t1;
    m0 = nm0; m1 = nm1;
    #pragma unroll 2
    for (int j = 0; j < nv; ++j) {
      int sj = __shfl(sidx, j);
      float pj0 = __shfl(p0, j), pj1 = __shfl(p1, j);
      float w = head ? pj1 : pj0;
      uint2 zv = ((const uint2*)(zb + (size_t)sj * 256))[lane];
      acc.x += w * bflo(zv.x); acc.y += w * bfhi(zv.x);
      acc.z += w * bflo(zv.y); acc.w += w * bfhi(zv.y);
    }
  }
  float inv0 = (l0 > 0.f) ? 1.f / l0 : 0.f;
  float inv1 = (l1 > 0.f) ? 1.f / l1 : 0.f;
  float inv = head ? inv1 : inv0;
  float4 b = ((const float4*)gat_bias)[lane];
  float4 o;
  o.x = fmaxf(acc.x * inv + b.x, 0.f);
  o.y = fmaxf(acc.y * inv + b.y, 0.f);
  o.z = fmaxf(acc.z * inv + b.z, 0.f);
  o.w = fmaxf(acc.w * inv + b.w, 0.f);
  ((float4*)(out + (size_t)node * 256))[lane] = o;
}

// ---------- parallel segmented per-graph sums ----------
__global__ __launch_bounds__(256) void k_segred(const float* __restrict__ hgat,
    const int* __restrict__ gidc, float* __restrict__ sums, int NT2) {
  int node0 = blockIdx.x * 128;
  int col = threadIdx.x;
  int end = node0 + 128; if (end > NT2) end = NT2;
  if (node0 >= NT2) return;
  float acc = 0.f;
  int gcur = gidc[node0];
  for (int n = node0; n < end; ++n) {
    int g = gidc[n];
    if (g != gcur) {
      atomicAdd(&sums[gcur * 256 + col], acc);
      acc = 0.f; gcur = g;
    }
    acc += hgat[(size_t)n * 256 + col];
  }
  atomicAdd(&sums[gcur * 256 + col], acc);
}

// ---------- mean + classifier ----------
__global__ __launch_bounds__(64) void k_classify(const float* __restrict__ sums,
    const int* __restrict__ gcnt, const float* __restrict__ W_cls,
    const float* __restrict__ b_cls, float* __restrict__ logits) {
  int g = blockIdx.x, tid = threadIdx.x;
  int hh = tid >> 5, c = tid & 31;
  float invc = 1.f / fmaxf((float)gcnt[g], 1.f);
  float acc = 0.f;
  for (int d = 0; d < D; ++d)
    acc += (sums[g * 256 + hh * D + d] * invc) * W_cls[c * D + d];
  logits[g * 64 + hh * 32 + c] = acc + b_cls[c];
}

// ---------- pairwise distance + softmax over heads (graph g vs g+64) ----------
__global__ __launch_bounds__(64) void k_final(const float* __restrict__ logits,
    float* __restrict__ out) {
  int g = threadIdx.x;
  if (g >= NG) return;
  float d[2];
  #pragma unroll
  for (int hh = 0; hh < 2; ++hh) {
    float s = 0.f;
    for (int c = 0; c < 32; ++c) {
      float df = logits[g * 64 + hh * 32 + c] - logits[(g + NG) * 64 + hh * 32 + c] + 1e-6f;
      s += df * df;
    }
    d[hh] = sqrtf(s);
  }
  float mx = fmaxf(d[0], d[1]);
  float e0 = expf(d[0] - mx), e1 = expf(d[1] - mx);
  float den = e0 + e1;
  out[g * 2] = e0 / den;
  out[g * 2 + 1] = e1 / den;
}

extern "C" void kernel_launch(void* const* d_in, const int* in_sizes, int n_in,
                              void* d_out, int out_size, void* d_ws, size_t ws_size,
                              hipStream_t stream) {
  const float* in_feat1 = (const float*)d_in[0];
  const float* in_feat2 = (const float*)d_in[1];
  const int* src1 = (const int*)d_in[2];
  const int* dst1 = (const int*)d_in[3];
  const int* ety1 = (const int*)d_in[4];
  const int* gid1 = (const int*)d_in[5];
  const int* src2 = (const int*)d_in[6];
  const int* dst2 = (const int*)d_in[7];
  const int* ety2 = (const int*)d_in[8];
  const int* gid2 = (const int*)d_in[9];
  const float* W_et = (const float*)d_in[10];
  const float* b_et = (const float*)d_in[11];
  const float* W_ih = (const float*)d_in[12];
  const float* W_hh = (const float*)d_in[13];
  const float* b_ih = (const float*)d_in[14];
  const float* b_hh = (const float*)d_in[15];
  const float* W_fc = (const float*)d_in[16];
  const float* attn_l = (const float*)d_in[17];
  const float* attn_r = (const float*)d_in[18];
  const float* gat_bias = (const float*)d_in[19];
  const float* W_cls = (const float*)d_in[20];
  const float* b_cls = (const float*)d_in[21];
  float* out = (float*)d_out;

  int N = in_sizes[0] / D;
  int E = in_sizes[2];
  int N2 = 2 * N, E2 = 2 * E;

  char* p = (char*)d_ws;
  auto alloc = [&](size_t bytes) -> void* {
    char* r = p;
    p += (bytes + 255) & ~(size_t)255;
    return (void*)r;
  };
  short* WetP = (short*)alloc((size_t)512 * 128 * 2);
  short* WihP = (short*)alloc((size_t)384 * 128 * 2);
  short* WhhP = (short*)alloc((size_t)384 * 128 * 2);
  short* WfcP = (short*)alloc((size_t)256 * 128 * 2);
  short* hb  = (short*)alloc((size_t)N2 * D * 2);
  short* ab  = (short*)alloc((size_t)N2 * D * 2);
  short* t   = (short*)alloc((size_t)N2 * 512 * 2);   // bf16 messages; reused as hgat
  short* zb  = (short*)alloc((size_t)N2 * 256 * 2);   // bf16 zft
  float* el  = (float*)alloc((size_t)N2 * 2 * 4);
  float* er  = (float*)alloc((size_t)N2 * 2 * 4);
  float* sums= (float*)alloc((size_t)NG2 * 256 * 4);
  float* logits = (float*)alloc((size_t)NG2 * 64 * 4);
  int* deg     = (int*)alloc((size_t)N2 * 4);
  int* row_ofs = (int*)alloc(((size_t)N2 + 1) * 4);
  int* cursor  = (int*)alloc((size_t)N2 * 4);
  int* gidc    = (int*)alloc((size_t)N2 * 4);
  int* gcnt    = (int*)alloc((size_t)NG2 * 4);
  int* bsum    = (int*)alloc((size_t)1024 * 4);
  int* boffs   = (int*)alloc((size_t)1024 * 4);
  int* csr_src = (int*)alloc((size_t)E2 * 4);
  int* csr_row = (int*)alloc((size_t)E2 * 4);
  if ((size_t)(p - (char*)d_ws) > ws_size) return;

  float* hgat = (float*)t;    // [N2,256] fp32 — overlays t (dead after last aggregate)

  // weight packing
  k_pack<<<dim3(64), dim3(256), 0, stream>>>(W_et, WetP, 512);
  k_pack<<<dim3(48), dim3(256), 0, stream>>>(W_ih, WihP, 384);
  k_pack<<<dim3(48), dim3(256), 0, stream>>>(W_hh, WhhP, 384);
  k_pack<<<dim3(32), dim3(256), 0, stream>>>(W_fc, WfcP, 256);

  // CSR for merged graph (hierarchical scan)
  hipMemsetAsync(deg, 0, (size_t)N2 * 4, stream);
  hipMemsetAsync(gcnt, 0, (size_t)NG2 * 4, stream);
  int eb = (E2 + 255) / 256;
  int nb = (N2 + 1023) / 1024;
  k_hist<<<dim3(eb), dim3(256), 0, stream>>>(dst1, dst2, E, N, deg);
  k_scan_a<<<dim3(nb), dim3(256), 0, stream>>>(deg, N2, bsum);
  k_scan_b<<<dim3(1), dim3(1024), 0, stream>>>(bsum, boffs, nb);
  k_scan_c<<<dim3(nb), dim3(256), 0, stream>>>(deg, boffs, row_ofs, cursor, N2);
  k_scatter<<<dim3(eb), dim3(256), 0, stream>>>(src1, dst1, ety1, src2, dst2, ety2,
                                                E, N, cursor, csr_src, csr_row);
  k_fillgid<<<dim3((N2 + 255) / 256, 1), dim3(256), 0, stream>>>(gid1, gid2, N, gidc, gcnt);

  // init h (bf16)
  k_init<<<dim3(1024), dim3(256), 0, stream>>>(in_feat1, in_feat2, hb, N * D / 4);

  int gb = (N2 + 127) / 128;
  int nb4 = (N2 + 3) / 4;

  for (int s = 0; s < NSTEPS; ++s) {
    k_mfma_gemm<32, true><<<dim3(gb), dim3(256), 0, stream>>>(hb, WetP, b_et, t, N2);
    k_aggregate<<<dim3(nb4), dim3(256), 0, stream>>>(t, row_ofs, csr_row, ab, N2);
    k_gru_mfma<<<dim3(gb), dim3(256), 0, stream>>>(ab, hb, WihP, WhhP, b_ih, b_hh, N2);
  }
  k_norm_sig<<<dim3(nb4), dim3(256), 0, stream>>>(hb, N2);
  k_fc_eler<<<dim3(gb), dim3(256), 0, stream>>>(hb, WfcP, attn_l, attn_r, zb, el, er, N2);
  k_gat<<<dim3(nb4), dim3(256), 0, stream>>>(zb, el, er, row_ofs, csr_src,
                                             gat_bias, hgat, N2);
  hipMemsetAsync(sums, 0, (size_t)NG2 * 256 * 4, stream);
  k_segred<<<dim3((N2 + 127) / 128), dim3(256), 0, stream>>>(hgat, gidc, sums, N2);
  k_classify<<<dim3(NG2), dim3(64), 0, stream>>>(sums, gcnt, W_cls, b_cls, logits);
  k_final<<<dim3(1), dim3(64), 0, stream>>>(logits, out);
}